// Round 3
// baseline (2545.025 us; speedup 1.0000x reference)
//
#include <hip/hip_runtime.h>
#include <math.h>

#define CCH 256
#define HEADS 8
#define DHH 32
#define BATCH 2
#define HDIM 256
#define WDIM 256
#define NPIX (HDIM*WDIM)          // 65536
#define PTOT (BATCH*NPIX)         // 131072
#define GCH 16                    // Gram split-K chunks per batch

// ---------------------------------------------------------------------------
// GEMM: C[M,256] = A[M,256] @ W (+bias) (optionally * emul elementwise)
// transb=0: W[k,n] row-major ; transb=1: W[n,k] row-major
// BM=128, BN=128, BK=16, 256 threads, 8x8 micro-tile.
// In-place safe when emul==Cmat (thread reads emul[row] then writes same addr).
// ---------------------------------------------------------------------------
#define BM 128
#define BN 128
#define BK 16
#define LDT 132

__global__ __launch_bounds__(256) void gemm_kernel(
    const float* __restrict__ A, const float* __restrict__ W,
    const float* __restrict__ bias, const float* __restrict__ emul,
    float* __restrict__ Cmat, int transb)
{
  __shared__ float As[BK][LDT];
  __shared__ float Bs[BK][LDT];
  const int t  = threadIdx.x;
  const int tx = t & 15;
  const int ty = t >> 4;
  const int m0 = blockIdx.x * BM;
  const int n0 = blockIdx.y * BN;

  float acc[8][8] = {};

  const int ar  = t >> 2;            // 0..63
  const int ak4 = (t & 3) << 2;      // 0,4,8,12
  const int bkr = t >> 4;            // 0..15
  const int bn8 = (t & 15) << 3;     // 0..120

  for (int k0 = 0; k0 < 256; k0 += BK) {
    const float* ap = A + (size_t)(m0 + ar) * 256 + k0 + ak4;
    float4 a0 = *(const float4*)ap;
    float4 a1 = *(const float4*)(ap + (size_t)64 * 256);
    float4 b0, b1;
    if (!transb) {
      const float* wp = W + (size_t)(k0 + bkr) * 256 + n0 + bn8;
      b0 = *(const float4*)wp;
      b1 = *(const float4*)(wp + 4);
    } else {
      const float* wp = W + (size_t)(n0 + ar) * 256 + k0 + ak4;
      b0 = *(const float4*)wp;
      b1 = *(const float4*)(wp + (size_t)64 * 256);
    }
    __syncthreads();   // protect previous tile's LDS reads
    As[ak4+0][ar]    = a0.x; As[ak4+1][ar]    = a0.y;
    As[ak4+2][ar]    = a0.z; As[ak4+3][ar]    = a0.w;
    As[ak4+0][ar+64] = a1.x; As[ak4+1][ar+64] = a1.y;
    As[ak4+2][ar+64] = a1.z; As[ak4+3][ar+64] = a1.w;
    if (!transb) {
      *(float4*)&Bs[bkr][bn8]     = b0;
      *(float4*)&Bs[bkr][bn8 + 4] = b1;
    } else {
      Bs[ak4+0][ar]    = b0.x; Bs[ak4+1][ar]    = b0.y;
      Bs[ak4+2][ar]    = b0.z; Bs[ak4+3][ar]    = b0.w;
      Bs[ak4+0][ar+64] = b1.x; Bs[ak4+1][ar+64] = b1.y;
      Bs[ak4+2][ar+64] = b1.z; Bs[ak4+3][ar+64] = b1.w;
    }
    __syncthreads();
    #pragma unroll
    for (int k = 0; k < BK; ++k) {
      float av[8], bv[8];
      *(float4*)&av[0] = *(const float4*)&As[k][ty*8];
      *(float4*)&av[4] = *(const float4*)&As[k][ty*8 + 4];
      *(float4*)&bv[0] = *(const float4*)&Bs[k][tx*8];
      *(float4*)&bv[4] = *(const float4*)&Bs[k][tx*8 + 4];
      #pragma unroll
      for (int i = 0; i < 8; ++i)
        #pragma unroll
        for (int j = 0; j < 8; ++j)
          acc[i][j] += av[i] * bv[j];
    }
  }

  #pragma unroll
  for (int i = 0; i < 8; ++i) {
    size_t row = (size_t)(m0 + ty*8 + i) * 256 + n0 + tx*8;
    float o[8];
    #pragma unroll
    for (int j = 0; j < 8; ++j) o[j] = acc[i][j];
    if (emul) {
      float4 e0 = *(const float4*)(emul + row);
      float4 e1 = *(const float4*)(emul + row + 4);
      o[0]*=e0.x; o[1]*=e0.y; o[2]*=e0.z; o[3]*=e0.w;
      o[4]*=e1.x; o[5]*=e1.y; o[6]*=e1.z; o[7]*=e1.w;
    }
    if (bias) {
      #pragma unroll
      for (int j = 0; j < 8; ++j) o[j] += bias[n0 + tx*8 + j];
    }
    *(float4*)(Cmat + row)     = make_float4(o[0], o[1], o[2], o[3]);
    *(float4*)(Cmat + row + 4) = make_float4(o[4], o[5], o[6], o[7]);
  }
}

// ---------------------------------------------------------------------------
// Gram partials: Gp[b][chunk][i][j] = sum_{n in chunk} x[n,i]*x[n,j]
// Upper-triangle 64x64 tiles only (10 pairs). 256 thr, 4x4 micro-tile.
// ---------------------------------------------------------------------------
__global__ __launch_bounds__(256) void syrk_partial(
    const float* __restrict__ X, float* __restrict__ Gp)
{
  __shared__ float xi[64][68];
  __shared__ float xj[64][68];
  const int TI[10] = {0,0,0,0,1,1,1,2,2,3};
  const int TJ[10] = {0,1,2,3,1,2,3,2,3,3};
  const int t = threadIdx.x;
  int blk = blockIdx.x;                 // b*(GCH*10) + chunk*10 + pair
  const int pair  = blk % 10;
  const int chunk = (blk / 10) % GCH;
  const int b     = blk / (10 * GCH);
  const int ti = TI[pair], tj = TJ[pair];
  const size_t xb = (size_t)b * NPIX * CCH;
  const int n0 = chunk * (NPIX / GCH);
  const int lr = t >> 2;                // 0..63
  const int lc = (t & 3) * 16;          // 0,16,32,48
  const int iy = (t >> 4) * 4;
  const int jx = (t & 15) * 4;
  float acc[4][4] = {};

  for (int pt = 0; pt < (NPIX / GCH) / 64; ++pt) {
    const float* xr = X + xb + (size_t)(n0 + pt*64 + lr) * 256;
    float4 vi[4], vj[4];
    #pragma unroll
    for (int s = 0; s < 4; ++s) {
      vi[s] = *(const float4*)(xr + ti*64 + lc + s*4);
      vj[s] = *(const float4*)(xr + tj*64 + lc + s*4);
    }
    __syncthreads();
    #pragma unroll
    for (int s = 0; s < 4; ++s) {
      *(float4*)&xi[lr][lc + s*4] = vi[s];
      *(float4*)&xj[lr][lc + s*4] = vj[s];
    }
    __syncthreads();
    #pragma unroll 8
    for (int p = 0; p < 64; ++p) {
      float av[4], bv[4];
      *(float4*)&av[0] = *(const float4*)&xi[p][iy];
      *(float4*)&bv[0] = *(const float4*)&xj[p][jx];
      #pragma unroll
      for (int i = 0; i < 4; ++i)
        #pragma unroll
        for (int j = 0; j < 4; ++j)
          acc[i][j] += av[i] * bv[j];
    }
  }
  float* g = Gp + (size_t)(b * GCH + chunk) * 65536;
  #pragma unroll
  for (int i = 0; i < 4; ++i)
    #pragma unroll
    for (int j = 0; j < 4; ++j)
      g[(ti*64 + iy + i) * 256 + (tj*64 + jx + j)] = acc[i][j];
}

// G[b][i][j] = sum_ch Gp[...], mirroring the unstored lower tiles.
__global__ __launch_bounds__(256) void syrk_reduce(
    const float* __restrict__ Gp, float* __restrict__ G)
{
  int flat = blockIdx.x * 256 + threadIdx.x;   // 0 .. 2*65536-1
  int b  = flat >> 16;
  int ij = flat & 65535;
  int i = ij >> 8, j = ij & 255;
  int src = ((i >> 6) <= (j >> 6)) ? (i*256 + j) : (j*256 + i);
  float s = 0.f;
  for (int ch = 0; ch < GCH; ++ch)
    s += Gp[(size_t)(b*GCH + ch) * 65536 + src];
  G[(size_t)b * 65536 + ij] = s;
}

// ---------------------------------------------------------------------------
// S[bh][d][e] = sum_c1 wk[c1][h*32+d] * TQ[b][c1][h*32+e]
// Rotation-swizzled LDS ([c1][(e+c1)&31]) to kill column bank conflicts.
// ---------------------------------------------------------------------------
__global__ __launch_bounds__(256) void headS_kernel(
    const float* __restrict__ wk, const float* __restrict__ TQ,
    float* __restrict__ S)
{
  __shared__ float wks[256][32];
  __shared__ float tqs[256][32];
  const int t  = threadIdx.x;          // c1
  const int bh = blockIdx.x;           // 0..15
  const int b = bh >> 3, h = bh & 7;
  const float* wkrow = wk + (size_t)t * 256 + h*32;
  const float* tqrow = TQ + (size_t)b * 65536 + (size_t)t * 256 + h*32;
  #pragma unroll
  for (int e = 0; e < 32; ++e) {
    wks[t][(e + t) & 31] = wkrow[e];
    tqs[t][(e + t) & 31] = tqrow[e];
  }
  __syncthreads();
  const int d  = t >> 3;
  const int e0 = (t & 7) * 4;
  float acc[4] = {0.f, 0.f, 0.f, 0.f};
  for (int c1 = 0; c1 < 256; ++c1) {
    float kv = wks[c1][(d + c1) & 31];
    #pragma unroll
    for (int j = 0; j < 4; ++j)
      acc[j] += kv * tqs[c1][(e0 + j + c1) & 31];
  }
  #pragma unroll
  for (int j = 0; j < 4; ++j)
    S[bh*1024 + d*32 + e0 + j] = acc[j];
}

// nq[b][o] = sum_c1 wq[c1][o]*TQ[b][c1][o] ; nk likewise with wk/TK (coalesced)
__global__ __launch_bounds__(256) void norms_kernel(
    const float* __restrict__ wq, const float* __restrict__ wk,
    const float* __restrict__ TQ, const float* __restrict__ TK,
    float* __restrict__ nq, float* __restrict__ nk)
{
  const int o = threadIdx.x;
  const int b = blockIdx.x;
  float sq = 0.f, sk = 0.f;
  for (int c1 = 0; c1 < 256; ++c1) {
    sq += wq[c1*256 + o] * TQ[(size_t)b*65536 + c1*256 + o];
    sk += wk[c1*256 + o] * TK[(size_t)b*65536 + c1*256 + o];
  }
  nq[b*256 + o] = sq;
  nk[b*256 + o] = sk;
}

// Normalize + rescale + softmax(axis=e)
__global__ __launch_bounds__(64) void attn_final(
    const float* __restrict__ S, const float* __restrict__ nq,
    const float* __restrict__ nk, const float* __restrict__ rescale,
    float* __restrict__ attn)
{
  const int bh = blockIdx.x;
  const int b = bh >> 3, h = bh & 7;
  const int d = threadIdx.x;
  if (d >= 32) return;
  const float r = rescale[h];
  const float nkd = fmaxf(sqrtf(nk[b*256 + h*32 + d]), 1e-12f);
  float vals[32];
  float mx = -1e30f;
  #pragma unroll
  for (int e = 0; e < 32; ++e) {
    float nqe = fmaxf(sqrtf(nq[b*256 + h*32 + e]), 1e-12f);
    float x = S[bh*1024 + d*32 + e] / (nkd * nqe) * r;
    vals[e] = x;
    mx = fmaxf(mx, x);
  }
  float sum = 0.f;
  #pragma unroll
  for (int e = 0; e < 32; ++e) { vals[e] = expf(vals[e] - mx); sum += vals[e]; }
  float inv = 1.f / sum;
  #pragma unroll
  for (int e = 0; e < 32; ++e) attn[bh*1024 + d*32 + e] = vals[e] * inv;
}

// Wb[b][h*32+e][o] = sum_d attn[b,h,d,e] * projw[h*32+d][o]
__global__ __launch_bounds__(256) void fold_proj(
    const float* __restrict__ attn, const float* __restrict__ projw,
    float* __restrict__ Wb)
{
  const int o  = threadIdx.x;
  const int he = blockIdx.x & 255;
  const int b  = blockIdx.x >> 8;
  const int h = he >> 5, e = he & 31;
  float acc = 0.f;
  #pragma unroll
  for (int d = 0; d < 32; ++d)
    acc += attn[((b*8 + h)*32 + d)*32 + e] * projw[(h*32 + d)*256 + o];
  Wb[(size_t)b*65536 + (size_t)he*256 + o] = acc;
}

// ---------------------------------------------------------------------------
// m <- m * (1 + sigmoid(dwconv5x5(t) + dwb))   (in-place on m)
// ---------------------------------------------------------------------------
__global__ __launch_bounds__(256) void mgm_kernel(
    const float* __restrict__ tin, float* __restrict__ m,
    const float* __restrict__ dww, const float* __restrict__ dwb)
{
  const int c  = threadIdx.x;
  const int blk = blockIdx.x;
  const int xc = (blk & 7) * 32;
  const int y  = (blk >> 3) & 255;
  const int b  = blk >> 11;
  float w[25];
  #pragma unroll
  for (int i = 0; i < 25; ++i) w[i] = dww[c*25 + i];
  const float bias = dwb[c];
  const size_t bb = (size_t)b * NPIX * CCH;
  for (int x = xc; x < xc + 32; ++x) {
    float conv = 0.f;
    #pragma unroll
    for (int dy = 0; dy < 5; ++dy) {
      int yy = y + dy - 2;
      if (yy < 0 || yy > 255) continue;
      #pragma unroll
      for (int dx = 0; dx < 5; ++dx) {
        int xx = x + dx - 2;
        if (xx < 0 || xx > 255) continue;
        conv += tin[bb + (size_t)(yy*256 + xx)*CCH + c] * w[dy*5 + dx];
      }
    }
    float sig = 1.f / (1.f + expf(-(conv + bias)));
    size_t i = bb + (size_t)(y*256 + x)*CCH + c;
    m[i] = m[i] * (1.f + sig);
  }
}

// p1 = gelu_exact(dwconv3x3(x_in, w1))
__global__ __launch_bounds__(256) void pos1_kernel(
    const float* __restrict__ xin, const float* __restrict__ w1,
    float* __restrict__ p1)
{
  const int c  = threadIdx.x;
  const int blk = blockIdx.x;
  const int xc = (blk & 7) * 32;
  const int y  = (blk >> 3) & 255;
  const int b  = blk >> 11;
  float w[9];
  #pragma unroll
  for (int i = 0; i < 9; ++i) w[i] = w1[c*9 + i];
  const size_t bb = (size_t)b * NPIX * CCH;
  for (int x = xc; x < xc + 32; ++x) {
    float conv = 0.f;
    #pragma unroll
    for (int dy = 0; dy < 3; ++dy) {
      int yy = y + dy - 1;
      if (yy < 0 || yy > 255) continue;
      #pragma unroll
      for (int dx = 0; dx < 3; ++dx) {
        int xx = x + dx - 1;
        if (xx < 0 || xx > 255) continue;
        conv += xin[bb + (size_t)(yy*256 + xx)*CCH + c] * w[dy*3 + dx];
      }
    }
    float g = 0.5f * conv * (1.f + erff(conv * 0.70710678118654752f));
    p1[bb + (size_t)(y*256 + x)*CCH + c] = g;
  }
}

// out += dwconv3x3(p1, w2)
__global__ __launch_bounds__(256) void pos2_kernel(
    const float* __restrict__ p1, const float* __restrict__ w2,
    float* __restrict__ out)
{
  const int c  = threadIdx.x;
  const int blk = blockIdx.x;
  const int xc = (blk & 7) * 32;
  const int y  = (blk >> 3) & 255;
  const int b  = blk >> 11;
  float w[9];
  #pragma unroll
  for (int i = 0; i < 9; ++i) w[i] = w2[c*9 + i];
  const size_t bb = (size_t)b * NPIX * CCH;
  for (int x = xc; x < xc + 32; ++x) {
    float conv = 0.f;
    #pragma unroll
    for (int dy = 0; dy < 3; ++dy) {
      int yy = y + dy - 1;
      if (yy < 0 || yy > 255) continue;
      #pragma unroll
      for (int dx = 0; dx < 3; ++dx) {
        int xx = x + dx - 1;
        if (xx < 0 || xx > 255) continue;
        conv += p1[bb + (size_t)(yy*256 + xx)*CCH + c] * w[dy*3 + dx];
      }
    }
    size_t i = bb + (size_t)(y*256 + x)*CCH + c;
    out[i] = out[i] + conv;
  }
}

// ---------------------------------------------------------------------------
extern "C" void kernel_launch(void* const* d_in, const int* in_sizes, int n_in,
                              void* d_out, int out_size, void* d_ws, size_t ws_size,
                              hipStream_t stream)
{
  const float* x_in   = (const float*)d_in[0];
  const float* mask   = (const float*)d_in[1];
  const float* wq     = (const float*)d_in[2];
  const float* wk     = (const float*)d_in[3];
  const float* wv     = (const float*)d_in[4];
  const float* rescal = (const float*)d_in[5];
  const float* proj_w = (const float*)d_in[6];
  const float* proj_b = (const float*)d_in[7];
  const float* pos_w1 = (const float*)d_in[8];
  const float* pos_w2 = (const float*)d_in[9];
  const float* c1w    = (const float*)d_in[10];
  const float* c1b    = (const float*)d_in[11];
  const float* c2w    = (const float*)d_in[12];
  const float* c2b    = (const float*)d_in[13];
  const float* dww    = (const float*)d_in[14];
  const float* dwb    = (const float*)d_in[15];
  float* OUT = (float*)d_out;

  // ws: ONE big buffer + Wb  (134.74 MB total)
  float* A  = (float*)d_ws;                     // PTOT*CCH = 33,554,432 fl
  float* Wb = A + (size_t)PTOT * CCH;           // 2*65536 fl

  // d_out doubles as scratch until the final projection GEMM overwrites it:
  float* Gp = OUT;                              // 2*GCH*65536 = 2,097,152 fl
  float* G  = OUT + 2097152;                    // 131072
  float* TQ = G  + 131072;                      // 131072
  float* TK = TQ + 131072;                      // 131072
  float* S  = TK + 131072;                      // 16384
  float* nq = S  + 16384;                       // 512
  float* nk = nq + 512;                         // 512
  float* at = nk + 512;                         // 16384

  dim3 gg(PTOT / BM, 2);

  // 1) mask path: A = mask @ c1w^T + c1b ; OUT = A @ c2w^T + c2b (t scratch)
  gemm_kernel<<<gg, 256, 0, stream>>>(mask, c1w, c1b, nullptr, A, 1);
  gemm_kernel<<<gg, 256, 0, stream>>>(A,    c2w, c2b, nullptr, OUT, 1);
  // 2) A <- A * (1 + sigmoid(dwconv5x5(OUT) + dwb))   == mask_attn
  mgm_kernel<<<4096, 256, 0, stream>>>(OUT, A, dww, dwb);
  // 3) Gram matrix G[b] = X[b]^T X[b]  (deterministic split-K, no atomics)
  syrk_partial<<<2 * GCH * 10, 256, 0, stream>>>(x_in, Gp);
  syrk_reduce<<<512, 256, 0, stream>>>(Gp, G);
  // 4) TQ = G @ wq, TK = G @ wk  (per batch; tiny GEMMs)
  {
    dim3 gs(2, 2);
    for (int b = 0; b < 2; ++b) {
      gemm_kernel<<<gs, 256, 0, stream>>>(G + (size_t)b*65536, wq, nullptr, nullptr,
                                          TQ + (size_t)b*65536, 0);
      gemm_kernel<<<gs, 256, 0, stream>>>(G + (size_t)b*65536, wk, nullptr, nullptr,
                                          TK + (size_t)b*65536, 0);
    }
  }
  // 5) S, norms, softmax, folded projection
  headS_kernel<<<16, 256, 0, stream>>>(wk, TQ, S);
  norms_kernel<<<2, 256, 0, stream>>>(wq, wk, TQ, TK, nq, nk);
  attn_final<<<16, 64, 0, stream>>>(S, nq, nk, rescal, at);
  fold_proj<<<512, 256, 0, stream>>>(at, proj_w, Wb);
  // 6) v' = (x @ wv) * mask_attn  — IN PLACE into A (emul==Cmat, race-free)
  gemm_kernel<<<gg, 256, 0, stream>>>(x_in, wv, nullptr, A, A, 0);
  // 7) OUT = v' @ Wb[b] + proj_b  (fully overwrites d_out incl. scratch)
  {
    dim3 gp(NPIX / BM, 2);
    for (int b = 0; b < 2; ++b)
      gemm_kernel<<<gp, 256, 0, stream>>>(A + (size_t)b * NPIX * CCH,
                                          Wb + (size_t)b * 65536,
                                          proj_b, nullptr,
                                          OUT + (size_t)b * NPIX * CCH, 0);
  }
  // 8) positional path: A = gelu(conv3(x_in)) ; OUT += conv3(A)
  pos1_kernel<<<4096, 256, 0, stream>>>(x_in, pos_w1, A);
  pos2_kernel<<<4096, 256, 0, stream>>>(A, pos_w2, OUT);
}

// Round 4
// 1464.578 us; speedup vs baseline: 1.7377x; 1.7377x over previous
//
#include <hip/hip_runtime.h>
#include <math.h>

#define CCH 256
#define HEADS 8
#define DHH 32
#define BATCH 2
#define HDIM 256
#define WDIM 256
#define NPIX (HDIM*WDIM)          // 65536
#define PTOT (BATCH*NPIX)         // 131072
#define GCH 64                    // Gram split-K chunks per batch

typedef __attribute__((ext_vector_type(8))) short bfrag;
typedef __attribute__((ext_vector_type(4))) float ffrag;

__device__ __forceinline__ unsigned short f2bf(float f) {
  unsigned u = __builtin_bit_cast(unsigned, f);
  u += 0x7fffu + ((u >> 16) & 1u);
  return (unsigned short)(u >> 16);
}
__device__ __forceinline__ float bf2f(unsigned short h) {
  unsigned u = (unsigned)h << 16;
  return __builtin_bit_cast(float, u);
}

// ---------------------------------------------------------------------------
// bf16x3 MFMA GEMM: C[M,256] = A[M,256] @ Wt^T (+bias) (optionally * emul)
// Wt is [n][k] row-major (n-major, k contiguous). Split A,W into hi+lo bf16;
// C = AhWh + AhWl + AlWh (drop AlWl ~ 2^-18) -> ~1e-5 rel error, fp32-like.
// BM=128, BN=128, BK=32, 256 threads = 4 waves, wave tile 64x64.
// In-place safe when emul==C (thread reads emul[idx] then writes same idx).
// ---------------------------------------------------------------------------
__global__ __launch_bounds__(256) void gemm_mfma(
    const float* __restrict__ A, const float* __restrict__ Wt,
    const float* __restrict__ bias, const float* __restrict__ emul,
    float* __restrict__ C)
{
  __shared__ unsigned short AsH[128][40];
  __shared__ unsigned short AsL[128][40];
  __shared__ unsigned short WsH[128][40];
  __shared__ unsigned short WsL[128][40];
  const int t = threadIdx.x;
  const int m0 = blockIdx.x * 128;
  const int n0 = blockIdx.y * 128;
  const int lane = t & 63;
  const int wave = t >> 6;
  const int wr = (wave >> 1) * 64;   // wave row base within tile
  const int wc = (wave & 1) * 64;    // wave col base
  const int sr = t >> 1;             // staging row 0..127
  const int sk = (t & 1) * 16;       // staging k base

  ffrag acc[4][4];
  #pragma unroll
  for (int i = 0; i < 4; ++i)
    #pragma unroll
    for (int j = 0; j < 4; ++j)
      acc[i][j] = (ffrag)0.f;

  const int fr = lane & 15;
  const int kc = (lane >> 4) * 8;

  for (int k0 = 0; k0 < 256; k0 += 32) {
    const float* ap = A  + (size_t)(m0 + sr) * 256 + k0 + sk;
    const float* wp = Wt + (size_t)(n0 + sr) * 256 + k0 + sk;
    float4 av[4], wv4[4];
    #pragma unroll
    for (int s = 0; s < 4; ++s) {
      av[s]  = *(const float4*)(ap + s*4);
      wv4[s] = *(const float4*)(wp + s*4);
    }
    __syncthreads();   // protect previous iteration's LDS reads
    #pragma unroll
    for (int s = 0; s < 4; ++s) {
      const float* a4 = (const float*)&av[s];
      const float* w4 = (const float*)&wv4[s];
      #pragma unroll
      for (int p = 0; p < 4; p += 2) {
        unsigned short h0 = f2bf(a4[p]), h1 = f2bf(a4[p+1]);
        unsigned short l0 = f2bf(a4[p]   - bf2f(h0));
        unsigned short l1 = f2bf(a4[p+1] - bf2f(h1));
        *(unsigned*)&AsH[sr][sk + s*4 + p] = (unsigned)h0 | ((unsigned)h1 << 16);
        *(unsigned*)&AsL[sr][sk + s*4 + p] = (unsigned)l0 | ((unsigned)l1 << 16);
        unsigned short g0 = f2bf(w4[p]), g1 = f2bf(w4[p+1]);
        unsigned short e0 = f2bf(w4[p]   - bf2f(g0));
        unsigned short e1 = f2bf(w4[p+1] - bf2f(g1));
        *(unsigned*)&WsH[sr][sk + s*4 + p] = (unsigned)g0 | ((unsigned)g1 << 16);
        *(unsigned*)&WsL[sr][sk + s*4 + p] = (unsigned)e0 | ((unsigned)e1 << 16);
      }
    }
    __syncthreads();
    bfrag ah[4], alo[4], bh[4], blo[4];
    #pragma unroll
    for (int i = 0; i < 4; ++i) {
      ah[i]  = *(const bfrag*)&AsH[wr + i*16 + fr][kc];
      alo[i] = *(const bfrag*)&AsL[wr + i*16 + fr][kc];
      bh[i]  = *(const bfrag*)&WsH[wc + i*16 + fr][kc];
      blo[i] = *(const bfrag*)&WsL[wc + i*16 + fr][kc];
    }
    #pragma unroll
    for (int i = 0; i < 4; ++i)
      #pragma unroll
      for (int j = 0; j < 4; ++j) {
        acc[i][j] = __builtin_amdgcn_mfma_f32_16x16x32_bf16(ah[i],  bh[j],  acc[i][j], 0, 0, 0);
        acc[i][j] = __builtin_amdgcn_mfma_f32_16x16x32_bf16(ah[i],  blo[j], acc[i][j], 0, 0, 0);
        acc[i][j] = __builtin_amdgcn_mfma_f32_16x16x32_bf16(alo[i], bh[j],  acc[i][j], 0, 0, 0);
      }
  }

  // C/D layout (m89-verified): col = lane&15, row = (lane>>4)*4 + reg
  const int er = (lane >> 4) * 4;
  const int ec = lane & 15;
  #pragma unroll
  for (int i = 0; i < 4; ++i) {
    #pragma unroll
    for (int j = 0; j < 4; ++j) {
      #pragma unroll
      for (int q = 0; q < 4; ++q) {
        int grow = m0 + wr + i*16 + er + q;
        int gcol = n0 + wc + j*16 + ec;
        size_t idx = (size_t)grow * 256 + gcol;
        float o = acc[i][j][q];
        if (emul) o *= emul[idx];
        if (bias) o += bias[gcol];
        C[idx] = o;
      }
    }
  }
}

// ---------------------------------------------------------------------------
// 256x256 fp32 transpose: dst[o][c] = src[c][o]
// ---------------------------------------------------------------------------
__global__ __launch_bounds__(256) void transpose256(
    const float* __restrict__ src, float* __restrict__ dst)
{
  __shared__ float tile[32][33];
  const int bx = blockIdx.x & 7, by = blockIdx.x >> 3;
  const int tx = threadIdx.x & 31, ty = threadIdx.x >> 5;
  #pragma unroll
  for (int s = 0; s < 32; s += 8)
    tile[ty + s][tx] = src[(by*32 + ty + s)*256 + bx*32 + tx];
  __syncthreads();
  #pragma unroll
  for (int s = 0; s < 32; s += 8)
    dst[(bx*32 + ty + s)*256 + by*32 + tx] = tile[tx][ty + s];
}

// ---------------------------------------------------------------------------
// Gram partials: Gp[b][chunk][i][j] = sum_{n in chunk} x[n,i]*x[n,j]
// Upper-triangle 64x64 tiles only (10 pairs). 256 thr, 4x4 micro-tile.
// ---------------------------------------------------------------------------
__global__ __launch_bounds__(256) void syrk_partial(
    const float* __restrict__ X, float* __restrict__ Gp)
{
  __shared__ float xi[64][68];
  __shared__ float xj[64][68];
  const int TI[10] = {0,0,0,0,1,1,1,2,2,3};
  const int TJ[10] = {0,1,2,3,1,2,3,2,3,3};
  const int t = threadIdx.x;
  int blk = blockIdx.x;                 // b*(GCH*10) + chunk*10 + pair
  const int pair  = blk % 10;
  const int chunk = (blk / 10) % GCH;
  const int b     = blk / (10 * GCH);
  const int ti = TI[pair], tj = TJ[pair];
  const size_t xb = (size_t)b * NPIX * CCH;
  const int n0 = chunk * (NPIX / GCH);
  const int lr = t >> 2;                // 0..63
  const int lc = (t & 3) * 16;          // 0,16,32,48
  const int iy = (t >> 4) * 4;
  const int jx = (t & 15) * 4;
  float acc[4][4] = {};

  for (int pt = 0; pt < (NPIX / GCH) / 64; ++pt) {
    const float* xr = X + xb + (size_t)(n0 + pt*64 + lr) * 256;
    float4 vi[4], vj[4];
    #pragma unroll
    for (int s = 0; s < 4; ++s) {
      vi[s] = *(const float4*)(xr + ti*64 + lc + s*4);
      vj[s] = *(const float4*)(xr + tj*64 + lc + s*4);
    }
    __syncthreads();
    #pragma unroll
    for (int s = 0; s < 4; ++s) {
      *(float4*)&xi[lr][lc + s*4] = vi[s];
      *(float4*)&xj[lr][lc + s*4] = vj[s];
    }
    __syncthreads();
    #pragma unroll 8
    for (int p = 0; p < 64; ++p) {
      float av[4], bv[4];
      *(float4*)&av[0] = *(const float4*)&xi[p][iy];
      *(float4*)&bv[0] = *(const float4*)&xj[p][jx];
      #pragma unroll
      for (int i = 0; i < 4; ++i)
        #pragma unroll
        for (int j = 0; j < 4; ++j)
          acc[i][j] += av[i] * bv[j];
    }
  }
  float* g = Gp + (size_t)(b * GCH + chunk) * 65536;
  #pragma unroll
  for (int i = 0; i < 4; ++i)
    #pragma unroll
    for (int j = 0; j < 4; ++j)
      g[(ti*64 + iy + i) * 256 + (tj*64 + jx + j)] = acc[i][j];
}

// G[b][i][j] = sum_ch Gp[...], mirroring the unstored lower tiles.
__global__ __launch_bounds__(256) void syrk_reduce(
    const float* __restrict__ Gp, float* __restrict__ G)
{
  int flat = blockIdx.x * 256 + threadIdx.x;   // 0 .. 2*65536-1
  int b  = flat >> 16;
  int ij = flat & 65535;
  int i = ij >> 8, j = ij & 255;
  int src = ((i >> 6) <= (j >> 6)) ? (i*256 + j) : (j*256 + i);
  float s = 0.f;
  for (int ch = 0; ch < GCH; ++ch)
    s += Gp[(size_t)(b*GCH + ch) * 65536 + src];
  G[(size_t)b * 65536 + ij] = s;
}

// ---------------------------------------------------------------------------
// S[bh][d][e] = sum_c1 wk[c1][h*32+d] * TQ[b][c1][h*32+e]
// ---------------------------------------------------------------------------
__global__ __launch_bounds__(256) void headS_kernel(
    const float* __restrict__ wk, const float* __restrict__ TQ,
    float* __restrict__ S)
{
  __shared__ float wks[256][32];
  __shared__ float tqs[256][32];
  const int t  = threadIdx.x;          // c1
  const int bh = blockIdx.x;           // 0..15
  const int b = bh >> 3, h = bh & 7;
  const float* wkrow = wk + (size_t)t * 256 + h*32;
  const float* tqrow = TQ + (size_t)b * 65536 + (size_t)t * 256 + h*32;
  #pragma unroll
  for (int e = 0; e < 32; ++e) {
    wks[t][(e + t) & 31] = wkrow[e];
    tqs[t][(e + t) & 31] = tqrow[e];
  }
  __syncthreads();
  const int d  = t >> 3;
  const int e0 = (t & 7) * 4;
  float acc[4] = {0.f, 0.f, 0.f, 0.f};
  for (int c1 = 0; c1 < 256; ++c1) {
    float kv = wks[c1][(d + c1) & 31];
    #pragma unroll
    for (int j = 0; j < 4; ++j)
      acc[j] += kv * tqs[c1][(e0 + j + c1) & 31];
  }
  #pragma unroll
  for (int j = 0; j < 4; ++j)
    S[bh*1024 + d*32 + e0 + j] = acc[j];
}

// norms partials over c1-chunks of 32
__global__ __launch_bounds__(256) void norms_part(
    const float* __restrict__ wq, const float* __restrict__ wk,
    const float* __restrict__ TQ, const float* __restrict__ TK,
    float* __restrict__ nqp, float* __restrict__ nkp)
{
  const int o = threadIdx.x;
  const int ch = blockIdx.x & 7;
  const int b  = blockIdx.x >> 3;
  float sq = 0.f, sk = 0.f;
  for (int c1 = ch*32; c1 < ch*32 + 32; ++c1) {
    sq += wq[c1*256 + o] * TQ[(size_t)b*65536 + c1*256 + o];
    sk += wk[c1*256 + o] * TK[(size_t)b*65536 + c1*256 + o];
  }
  nqp[(b*8 + ch)*256 + o] = sq;
  nkp[(b*8 + ch)*256 + o] = sk;
}

__global__ __launch_bounds__(256) void norms_comb(
    const float* __restrict__ nqp, const float* __restrict__ nkp,
    float* __restrict__ nq, float* __restrict__ nk)
{
  int flat = blockIdx.x * 256 + threadIdx.x;   // 0..511
  int b = flat >> 8, o = flat & 255;
  float sq = 0.f, sk = 0.f;
  #pragma unroll
  for (int ch = 0; ch < 8; ++ch) {
    sq += nqp[(b*8 + ch)*256 + o];
    sk += nkp[(b*8 + ch)*256 + o];
  }
  nq[flat] = sq;
  nk[flat] = sk;
}

// Normalize + rescale + softmax(axis=e)
__global__ __launch_bounds__(64) void attn_final(
    const float* __restrict__ S, const float* __restrict__ nq,
    const float* __restrict__ nk, const float* __restrict__ rescale,
    float* __restrict__ attn)
{
  const int bh = blockIdx.x;
  const int b = bh >> 3, h = bh & 7;
  const int d = threadIdx.x;
  if (d >= 32) return;
  const float r = rescale[h];
  const float nkd = fmaxf(sqrtf(nk[b*256 + h*32 + d]), 1e-12f);
  float vals[32];
  float mx = -1e30f;
  #pragma unroll
  for (int e = 0; e < 32; ++e) {
    float nqe = fmaxf(sqrtf(nq[b*256 + h*32 + e]), 1e-12f);
    float x = S[bh*1024 + d*32 + e] / (nkd * nqe) * r;
    vals[e] = x;
    mx = fmaxf(mx, x);
  }
  float sum = 0.f;
  #pragma unroll
  for (int e = 0; e < 32; ++e) { vals[e] = expf(vals[e] - mx); sum += vals[e]; }
  float inv = 1.f / sum;
  #pragma unroll
  for (int e = 0; e < 32; ++e) attn[bh*1024 + d*32 + e] = vals[e] * inv;
}

// WbT[b][o][h*32+e] = sum_d attn[b,h,d,e] * projw[h*32+d][o]  (n-major for gemm)
__global__ __launch_bounds__(256) void fold_proj(
    const float* __restrict__ attn, const float* __restrict__ projw,
    float* __restrict__ WbT)
{
  const int o  = threadIdx.x;
  const int he = blockIdx.x & 255;
  const int b  = blockIdx.x >> 8;
  const int h = he >> 5, e = he & 31;
  float acc = 0.f;
  #pragma unroll
  for (int d = 0; d < 32; ++d)
    acc += attn[((b*8 + h)*32 + d)*32 + e] * projw[(h*32 + d)*256 + o];
  WbT[(size_t)b*65536 + (size_t)o*256 + he] = acc;
}

// ---------------------------------------------------------------------------
// m <- m * (1 + sigmoid(dwconv5x5(t) + dwb))  — sliding-window, 5 loads/pixel
// ---------------------------------------------------------------------------
__global__ __launch_bounds__(256) void mgm_kernel(
    const float* __restrict__ tin, float* __restrict__ m,
    const float* __restrict__ dww, const float* __restrict__ dwb)
{
  const int c  = threadIdx.x;
  const int blk = blockIdx.x;
  const int xc = (blk & 7) * 32;
  const int y  = (blk >> 3) & 255;
  const int b  = blk >> 11;
  float w[25];
  #pragma unroll
  for (int i = 0; i < 25; ++i) w[i] = dww[c*25 + i];
  const float bias = dwb[c];
  const float* base = tin + (size_t)b * NPIX * CCH + c;
  int yo[5];
  #pragma unroll
  for (int dy = 0; dy < 5; ++dy) {
    int yy = y + dy - 2;
    yo[dy] = (yy >= 0 && yy <= 255) ? yy * 65536 : -1;
  }
  float col[5][5];
  #pragma unroll
  for (int j = 0; j < 4; ++j) {
    int xx = xc - 2 + j;
    bool xv = (xx >= 0 && xx <= 255);
    #pragma unroll
    for (int dy = 0; dy < 5; ++dy)
      col[j][dy] = (xv && yo[dy] >= 0) ? base[yo[dy] + xx*256] : 0.f;
  }
  size_t mi = (size_t)b * NPIX * CCH + ((size_t)y*256 + xc)*256 + c;
  #pragma unroll 4
  for (int xi = 0; xi < 32; ++xi) {
    int xx = xc + xi + 2;
    bool xv = (xx <= 255);
    #pragma unroll
    for (int dy = 0; dy < 5; ++dy)
      col[4][dy] = (xv && yo[dy] >= 0) ? base[yo[dy] + xx*256] : 0.f;
    float conv = 0.f;
    #pragma unroll
    for (int dy = 0; dy < 5; ++dy)
      #pragma unroll
      for (int j = 0; j < 5; ++j)
        conv += col[j][dy] * w[dy*5 + j];
    float sig = 1.f / (1.f + expf(-(conv + bias)));
    m[mi] = m[mi] * (1.f + sig);
    mi += 256;
    #pragma unroll
    for (int j = 0; j < 4; ++j)
      #pragma unroll
      for (int dy = 0; dy < 5; ++dy)
        col[j][dy] = col[j+1][dy];
  }
}

// p1 = gelu_exact(dwconv3x3(x_in, w1)) — sliding-window, 3 loads/pixel
__global__ __launch_bounds__(256) void pos1_kernel(
    const float* __restrict__ xin, const float* __restrict__ w1,
    float* __restrict__ p1)
{
  const int c  = threadIdx.x;
  const int blk = blockIdx.x;
  const int xc = (blk & 7) * 32;
  const int y  = (blk >> 3) & 255;
  const int b  = blk >> 11;
  float w[9];
  #pragma unroll
  for (int i = 0; i < 9; ++i) w[i] = w1[c*9 + i];
  const float* base = xin + (size_t)b * NPIX * CCH + c;
  int yo[3];
  #pragma unroll
  for (int dy = 0; dy < 3; ++dy) {
    int yy = y + dy - 1;
    yo[dy] = (yy >= 0 && yy <= 255) ? yy * 65536 : -1;
  }
  float col[3][3];
  #pragma unroll
  for (int j = 0; j < 2; ++j) {
    int xx = xc - 1 + j;
    bool xv = (xx >= 0 && xx <= 255);
    #pragma unroll
    for (int dy = 0; dy < 3; ++dy)
      col[j][dy] = (xv && yo[dy] >= 0) ? base[yo[dy] + xx*256] : 0.f;
  }
  size_t pi = (size_t)b * NPIX * CCH + ((size_t)y*256 + xc)*256 + c;
  #pragma unroll 4
  for (int xi = 0; xi < 32; ++xi) {
    int xx = xc + xi + 1;
    bool xv = (xx <= 255);
    #pragma unroll
    for (int dy = 0; dy < 3; ++dy)
      col[2][dy] = (xv && yo[dy] >= 0) ? base[yo[dy] + xx*256] : 0.f;
    float conv = 0.f;
    #pragma unroll
    for (int dy = 0; dy < 3; ++dy)
      #pragma unroll
      for (int j = 0; j < 3; ++j)
        conv += col[j][dy] * w[dy*3 + j];
    float g = 0.5f * conv * (1.f + erff(conv * 0.70710678118654752f));
    p1[pi] = g;
    pi += 256;
    #pragma unroll
    for (int j = 0; j < 2; ++j)
      #pragma unroll
      for (int dy = 0; dy < 3; ++dy)
        col[j][dy] = col[j+1][dy];
  }
}

// out += dwconv3x3(p1, w2) — sliding-window
__global__ __launch_bounds__(256) void pos2_kernel(
    const float* __restrict__ p1, const float* __restrict__ w2,
    float* __restrict__ out)
{
  const int c  = threadIdx.x;
  const int blk = blockIdx.x;
  const int xc = (blk & 7) * 32;
  const int y  = (blk >> 3) & 255;
  const int b  = blk >> 11;
  float w[9];
  #pragma unroll
  for (int i = 0; i < 9; ++i) w[i] = w2[c*9 + i];
  const float* base = p1 + (size_t)b * NPIX * CCH + c;
  int yo[3];
  #pragma unroll
  for (int dy = 0; dy < 3; ++dy) {
    int yy = y + dy - 1;
    yo[dy] = (yy >= 0 && yy <= 255) ? yy * 65536 : -1;
  }
  float col[3][3];
  #pragma unroll
  for (int j = 0; j < 2; ++j) {
    int xx = xc - 1 + j;
    bool xv = (xx >= 0 && xx <= 255);
    #pragma unroll
    for (int dy = 0; dy < 3; ++dy)
      col[j][dy] = (xv && yo[dy] >= 0) ? base[yo[dy] + xx*256] : 0.f;
  }
  size_t pi = (size_t)b * NPIX * CCH + ((size_t)y*256 + xc)*256 + c;
  #pragma unroll 4
  for (int xi = 0; xi < 32; ++xi) {
    int xx = xc + xi + 1;
    bool xv = (xx <= 255);
    #pragma unroll
    for (int dy = 0; dy < 3; ++dy)
      col[2][dy] = (xv && yo[dy] >= 0) ? base[yo[dy] + xx*256] : 0.f;
    float conv = 0.f;
    #pragma unroll
    for (int dy = 0; dy < 3; ++dy)
      #pragma unroll
      for (int j = 0; j < 3; ++j)
        conv += col[j][dy] * w[dy*3 + j];
    out[pi] = out[pi] + conv;
    pi += 256;
    #pragma unroll
    for (int j = 0; j < 2; ++j)
      #pragma unroll
      for (int dy = 0; dy < 3; ++dy)
        col[j][dy] = col[j+1][dy];
  }
}

// ---------------------------------------------------------------------------
extern "C" void kernel_launch(void* const* d_in, const int* in_sizes, int n_in,
                              void* d_out, int out_size, void* d_ws, size_t ws_size,
                              hipStream_t stream)
{
  const float* x_in   = (const float*)d_in[0];
  const float* mask   = (const float*)d_in[1];
  const float* wq     = (const float*)d_in[2];
  const float* wk     = (const float*)d_in[3];
  const float* wv     = (const float*)d_in[4];
  const float* rescal = (const float*)d_in[5];
  const float* proj_w = (const float*)d_in[6];
  const float* proj_b = (const float*)d_in[7];
  const float* pos_w1 = (const float*)d_in[8];
  const float* pos_w2 = (const float*)d_in[9];
  const float* c1w    = (const float*)d_in[10];
  const float* c1b    = (const float*)d_in[11];
  const float* c2w    = (const float*)d_in[12];
  const float* c2b    = (const float*)d_in[13];
  const float* dww    = (const float*)d_in[14];
  const float* dwb    = (const float*)d_in[15];
  float* OUT = (float*)d_out;

  // ws: big A buffer + WbT  (134.74 MB, same footprint as the passing run)
  float* A   = (float*)d_ws;                    // PTOT*CCH floats
  float* WbT = A + (size_t)PTOT * CCH;          // 2*65536

  // d_out doubles as scratch until step 13 overwrites it (t dead after mgm):
  float* Gp  = OUT;                             // 2*GCH*65536 = 8,388,608
  float* G   = OUT + 8388608;                   // 131072
  float* TQ  = G   + 131072;                    // 131072
  float* TK  = TQ  + 131072;                    // 131072
  float* S   = TK  + 131072;                    // 16384
  float* nqp = S   + 16384;                     // 4096
  float* nkp = nqp + 4096;                      // 4096
  float* nq  = nkp + 4096;                      // 512
  float* nk  = nq  + 512;                       // 512
  float* at  = nk  + 512;                       // 16384
  float* wvT = at  + 16384;                     // 65536
  float* wqT = wvT + 65536;                     // 65536
  float* wkT = wqT + 65536;                     // 65536

  dim3 gg(PTOT / 128, 2);

  // 1) mask path: A = mask @ c1w^T + c1b ; OUT(t) = A @ c2w^T + c2b
  //    (c1w/c2w are [out][in] row-major == n-major Wt directly)
  gemm_mfma<<<gg, 256, 0, stream>>>(mask, c1w, c1b, nullptr, A);
  gemm_mfma<<<gg, 256, 0, stream>>>(A,    c2w, c2b, nullptr, OUT);
  // 2) A <- A * (1 + sigmoid(dwconv5x5(t) + dwb))  == mask_attn
  mgm_kernel<<<4096, 256, 0, stream>>>(OUT, A, dww, dwb);
  // 3) weight transposes into OUT scratch (t is dead now)
  transpose256<<<64, 256, 0, stream>>>(wv, wvT);
  transpose256<<<64, 256, 0, stream>>>(wq, wqT);
  transpose256<<<64, 256, 0, stream>>>(wk, wkT);
  // 4) Gram matrix G[b] = X[b]^T X[b]  (deterministic split-K, no atomics)
  syrk_partial<<<2 * GCH * 10, 256, 0, stream>>>(x_in, Gp);
  syrk_reduce<<<512, 256, 0, stream>>>(Gp, G);
  // 5) TQ = G @ wq, TK = G @ wk  (per batch, MFMA)
  for (int b = 0; b < 2; ++b) {
    gemm_mfma<<<dim3(2,2), 256, 0, stream>>>(G + (size_t)b*65536, wqT, nullptr, nullptr, TQ + (size_t)b*65536);
    gemm_mfma<<<dim3(2,2), 256, 0, stream>>>(G + (size_t)b*65536, wkT, nullptr, nullptr, TK + (size_t)b*65536);
  }
  // 6) S, norms, softmax, folded (transposed) projection
  headS_kernel<<<16, 256, 0, stream>>>(wk, TQ, S);
  norms_part<<<16, 256, 0, stream>>>(wq, wk, TQ, TK, nqp, nkp);
  norms_comb<<<2, 256, 0, stream>>>(nqp, nkp, nq, nk);
  attn_final<<<16, 64, 0, stream>>>(S, nq, nk, rescal, at);
  fold_proj<<<512, 256, 0, stream>>>(at, proj_w, WbT);
  // 7) v' = (x @ wv) * mask_attn  — IN PLACE into A (emul==C, race-free)
  gemm_mfma<<<gg, 256, 0, stream>>>(x_in, wvT, nullptr, A, A);
  // 8) OUT = v' @ Wb[b] + proj_b  (fully overwrites d_out incl. scratch)
  {
    dim3 gp(NPIX / 128, 2);
    for (int b = 0; b < 2; ++b)
      gemm_mfma<<<gp, 256, 0, stream>>>(A + (size_t)b * NPIX * CCH,
                                        WbT + (size_t)b * 65536,
                                        proj_b, nullptr,
                                        OUT + (size_t)b * NPIX * CCH);
  }
  // 9) positional path: A = gelu(conv3(x_in)) ; OUT += conv3(A)
  pos1_kernel<<<4096, 256, 0, stream>>>(x_in, pos_w1, A);
  pos2_kernel<<<4096, 256, 0, stream>>>(A, pos_w2, OUT);
}

// Round 5
// 1435.187 us; speedup vs baseline: 1.7733x; 1.0205x over previous
//
#include <hip/hip_runtime.h>
#include <math.h>

#define CCH 256
#define HEADS 8
#define BATCH 2
#define NPIX 65536
#define PTOT 131072
#define NCH 128                 // syrk K-chunks per batch (512 pixels each)

typedef __attribute__((ext_vector_type(8))) short bfrag;
typedef __attribute__((ext_vector_type(4))) float ffrag;
typedef unsigned short u16;

// k-group swizzle: group g of row stored at short-offset KSW(row,g) (8 shorts/group)
#define KSW(row, g) ((((g) ^ (((row) >> 3) & 3)) << 3))

__device__ __forceinline__ float trunc_bf(float f) {
  unsigned u = __builtin_bit_cast(unsigned, f) & 0xffff0000u;
  return __builtin_bit_cast(float, u);
}
// pack hi16 of two floats: low short <- f0, high short <- f1 (bf16 truncation)
__device__ __forceinline__ unsigned pack_hi(float f0, float f1) {
  return __builtin_amdgcn_perm(__builtin_bit_cast(unsigned, f1),
                               __builtin_bit_cast(unsigned, f0), 0x07060302u);
}
__device__ __forceinline__ void split2(float f0, float f1, unsigned& h, unsigned& l) {
  h = pack_hi(f0, f1);
  l = pack_hi(f0 - trunc_bf(f0), f1 - trunc_bf(f1));
}

// ---------------------------------------------------------------------------
// bf16x3 MFMA GEMM: C[M,256] = A[M,256] @ W^T (+bias) (optionally * emul)
// W given pre-split as WH/WL bf16 [n][k] row-major. A split inline (trunc).
// BM=BN=128, BK=32, 256 thr = 4 waves (2x2 of 64x64). Reg-prefetch next tile.
// In-place safe when emul==C (same thread reads emul[idx] then writes idx).
// ---------------------------------------------------------------------------
__global__ __launch_bounds__(256) void gemm_mfma(
    const float* __restrict__ A, const u16* __restrict__ WH,
    const u16* __restrict__ WL, const float* __restrict__ bias,
    const float* __restrict__ emul, float* __restrict__ C)
{
  __shared__ u16 AsH[128][40], AsL[128][40], WsH[128][40], WsL[128][40];
  const int t = threadIdx.x;
  const int m0 = blockIdx.x * 128, n0 = blockIdx.y * 128;
  const int lane = t & 63, wave = t >> 6;
  const int wr = (wave >> 1) * 64, wc = (wave & 1) * 64;
  const int sr = t >> 1;               // staging row 0..127
  const int g0 = (t & 1) * 2;          // first of two k-groups this thread stages
  const int fr = lane & 15, kcg = lane >> 4;

  const float* ap  = A  + (size_t)(m0 + sr) * 256 + g0 * 8;
  const u16*   whp = WH + (size_t)(n0 + sr) * 256 + g0 * 8;
  const u16*   wlp = WL + (size_t)(n0 + sr) * 256 + g0 * 8;

  ffrag acc[4][4];
  #pragma unroll
  for (int i = 0; i < 4; ++i)
    #pragma unroll
    for (int j = 0; j < 4; ++j) acc[i][j] = (ffrag)0.f;

  float4 av[4]; uint4 whv[2], wlv[2];
  auto LOADT = [&](int k0) {
    #pragma unroll
    for (int s = 0; s < 4; ++s) av[s] = *(const float4*)(ap + k0 + s * 4);
    whv[0] = *(const uint4*)(whp + k0);
    whv[1] = *(const uint4*)(whp + k0 + 8);
    wlv[0] = *(const uint4*)(wlp + k0);
    wlv[1] = *(const uint4*)(wlp + k0 + 8);
  };
  LOADT(0);

  for (int k0 = 0; k0 < 256; k0 += 32) {
    __syncthreads();                       // prior compute done reading LDS
    unsigned h[8], l[8];
    #pragma unroll
    for (int s = 0; s < 4; ++s) {
      split2(av[s].x, av[s].y, h[2*s],   l[2*s]);
      split2(av[s].z, av[s].w, h[2*s+1], l[2*s+1]);
    }
    *(uint4*)&AsH[sr][KSW(sr, g0)]     = make_uint4(h[0], h[1], h[2], h[3]);
    *(uint4*)&AsH[sr][KSW(sr, g0 + 1)] = make_uint4(h[4], h[5], h[6], h[7]);
    *(uint4*)&AsL[sr][KSW(sr, g0)]     = make_uint4(l[0], l[1], l[2], l[3]);
    *(uint4*)&AsL[sr][KSW(sr, g0 + 1)] = make_uint4(l[4], l[5], l[6], l[7]);
    *(uint4*)&WsH[sr][KSW(sr, g0)]     = whv[0];
    *(uint4*)&WsH[sr][KSW(sr, g0 + 1)] = whv[1];
    *(uint4*)&WsL[sr][KSW(sr, g0)]     = wlv[0];
    *(uint4*)&WsL[sr][KSW(sr, g0 + 1)] = wlv[1];
    __syncthreads();
    if (k0 < 224) LOADT(k0 + 32);          // prefetch hides under MFMA

    bfrag ah[4], al_[4], bh[4], bl_[4];
    #pragma unroll
    for (int i = 0; i < 4; ++i) {
      int ra = wr + i * 16 + fr, rb = wc + i * 16 + fr;
      ah[i]  = *(const bfrag*)&AsH[ra][KSW(ra, kcg)];
      al_[i] = *(const bfrag*)&AsL[ra][KSW(ra, kcg)];
      bh[i]  = *(const bfrag*)&WsH[rb][KSW(rb, kcg)];
      bl_[i] = *(const bfrag*)&WsL[rb][KSW(rb, kcg)];
    }
    #pragma unroll
    for (int i = 0; i < 4; ++i)
      #pragma unroll
      for (int j = 0; j < 4; ++j) {
        acc[i][j] = __builtin_amdgcn_mfma_f32_16x16x32_bf16(ah[i],  bh[j],  acc[i][j], 0, 0, 0);
        acc[i][j] = __builtin_amdgcn_mfma_f32_16x16x32_bf16(ah[i],  bl_[j], acc[i][j], 0, 0, 0);
        acc[i][j] = __builtin_amdgcn_mfma_f32_16x16x32_bf16(al_[i], bh[j],  acc[i][j], 0, 0, 0);
      }
  }

  // C/D layout (HW-verified): col = lane&15, row = (lane>>4)*4 + reg
  const int er = (lane >> 4) * 4, ec = lane & 15;
  #pragma unroll
  for (int i = 0; i < 4; ++i)
    #pragma unroll
    for (int j = 0; j < 4; ++j)
      #pragma unroll
      for (int q = 0; q < 4; ++q) {
        int grow = m0 + wr + i * 16 + er + q;
        int gcol = n0 + wc + j * 16 + ec;
        size_t idx = (size_t)grow * 256 + gcol;
        float o = acc[i][j][q];
        if (emul) o *= emul[idx];
        if (bias) o += bias[gcol];
        C[idx] = o;
      }
}

// ---------------------------------------------------------------------------
// SYRK via MFMA: Gp[blk][256][256] = X_chunk^T X_chunk  (full, no symmetry)
// 512 thr = 8 waves; wave w owns rows w*32..w*32+31 x all 256 cols.
// A and B fragments read the SAME staged X^T tile. bf16 hi/lo x3.
// ---------------------------------------------------------------------------
__global__ __launch_bounds__(512, 2) void syrk_mfma(
    const float* __restrict__ X, float* __restrict__ Gp)
{
  __shared__ u16 XsH[256][40], XsL[256][40];
  const int t = threadIdx.x;
  const int blk = blockIdx.x;            // b*NCH + chunk
  const int chunk = blk & (NCH - 1);
  const int b = blk >> 7;                // NCH == 128
  const size_t xb = (size_t)b * NPIX * CCH;
  const int nbase = chunk * (NPIX / NCH);      // 512 pixels per chunk
  const int lane = t & 63, wave = t >> 6;
  const int r0 = wave * 32;
  const int fr = lane & 15, kcg = lane >> 4;
  const int cw = t & 31;                 // staging: c = cw + 32*j  (spacing 1!)
  const int n2 = (t >> 5) * 2;           // staging n-pair 0,2,..,30
  const int gst = n2 >> 3, nin = n2 & 7;

  ffrag acc[2][16];
  #pragma unroll
  for (int i = 0; i < 2; ++i)
    #pragma unroll
    for (int j = 0; j < 16; ++j) acc[i][j] = (ffrag)0.f;

  float fa[8], fb[8];
  auto LOADT = [&](int it) {
    const float* xr = X + xb + (size_t)(nbase + it * 32 + n2) * 256 + cw;
    #pragma unroll
    for (int j = 0; j < 8; ++j) { fa[j] = xr[32 * j]; fb[j] = xr[256 + 32 * j]; }
  };
  LOADT(0);

  const int NIT = (NPIX / NCH) / 32;     // 16
  for (int it = 0; it < NIT; ++it) {
    __syncthreads();
    #pragma unroll
    for (int j = 0; j < 8; ++j) {
      unsigned h, l;
      split2(fa[j], fb[j], h, l);        // low short <- row n2, high <- n2+1
      int c = cw + 32 * j;
      *(unsigned*)&XsH[c][KSW(c, gst) + nin] = h;
      *(unsigned*)&XsL[c][KSW(c, gst) + nin] = l;
    }
    __syncthreads();
    if (it + 1 < NIT) LOADT(it + 1);

    bfrag aH[2], aL[2];
    #pragma unroll
    for (int i = 0; i < 2; ++i) {
      int row = r0 + i * 16 + fr;
      aH[i] = *(const bfrag*)&XsH[row][KSW(row, kcg)];
      aL[i] = *(const bfrag*)&XsL[row][KSW(row, kcg)];
    }
    #pragma unroll
    for (int j = 0; j < 16; ++j) {
      int row = j * 16 + fr;
      bfrag bH = *(const bfrag*)&XsH[row][KSW(row, kcg)];
      bfrag bL = *(const bfrag*)&XsL[row][KSW(row, kcg)];
      #pragma unroll
      for (int i = 0; i < 2; ++i) {
        acc[i][j] = __builtin_amdgcn_mfma_f32_16x16x32_bf16(aH[i], bH, acc[i][j], 0, 0, 0);
        acc[i][j] = __builtin_amdgcn_mfma_f32_16x16x32_bf16(aH[i], bL, acc[i][j], 0, 0, 0);
        acc[i][j] = __builtin_amdgcn_mfma_f32_16x16x32_bf16(aL[i], bH, acc[i][j], 0, 0, 0);
      }
    }
  }
  float* g = Gp + (size_t)blk * 65536;
  const int er = (lane >> 4) * 4, ec = lane & 15;
  #pragma unroll
  for (int i = 0; i < 2; ++i)
    #pragma unroll
    for (int j = 0; j < 16; ++j)
      #pragma unroll
      for (int q = 0; q < 4; ++q)
        g[(r0 + i * 16 + er + q) * 256 + j * 16 + ec] = acc[i][j][q];
}

// G[b] = sum_ch Gp[b][ch]
__global__ __launch_bounds__(256) void syrk_reduce(
    const float* __restrict__ Gp, float* __restrict__ G)
{
  int id = blockIdx.x * 256 + threadIdx.x;   // 0..32767 (float4 units)
  int b = id >> 14;
  int i4 = id & 16383;
  const float4* src = (const float4*)(Gp + (size_t)b * NCH * 65536) + i4;
  float4 s = make_float4(0.f, 0.f, 0.f, 0.f);
  for (int ch = 0; ch < NCH; ++ch) {
    float4 v = src[(size_t)ch * 16384];
    s.x += v.x; s.y += v.y; s.z += v.z; s.w += v.w;
  }
  ((float4*)(G + (size_t)b * 65536))[i4] = s;
}

// ---------------------------------------------------------------------------
// weight preps: split fp32 -> bf16 H/L (direct: [o][c] kept; trans: [c][o]->[o][c])
// ---------------------------------------------------------------------------
__global__ __launch_bounds__(256) void prep_direct(
    const float* __restrict__ src, u16* __restrict__ H, u16* __restrict__ L)
{
  int id = blockIdx.x * 256 + threadIdx.x;
  float f = src[id];
  H[id] = (u16)(__builtin_bit_cast(unsigned, f) >> 16);
  float r = f - trunc_bf(f);
  L[id] = (u16)(__builtin_bit_cast(unsigned, r) >> 16);
}

__global__ __launch_bounds__(256) void prep_trans(
    const float* __restrict__ src, u16* __restrict__ H, u16* __restrict__ L)
{
  __shared__ float tile[32][33];
  const int bx = blockIdx.x & 7, by = blockIdx.x >> 3;
  const int tx = threadIdx.x & 31, ty = threadIdx.x >> 5;
  #pragma unroll
  for (int s = 0; s < 32; s += 8)
    tile[ty + s][tx] = src[(by * 32 + ty + s) * 256 + bx * 32 + tx];
  __syncthreads();
  #pragma unroll
  for (int s = 0; s < 32; s += 8) {
    float f = tile[tx][ty + s];
    int o = bx * 32 + ty + s, c = by * 32 + tx;
    H[o * 256 + c] = (u16)(__builtin_bit_cast(unsigned, f) >> 16);
    float r = f - trunc_bf(f);
    L[o * 256 + c] = (u16)(__builtin_bit_cast(unsigned, r) >> 16);
  }
}

// ---------------------------------------------------------------------------
// S[bh][d][e] = sum_c1 wk[c1][h*32+d] * TQ[b][c1][h*32+e]
// ---------------------------------------------------------------------------
__global__ __launch_bounds__(256) void headS_kernel(
    const float* __restrict__ wk, const float* __restrict__ TQ,
    float* __restrict__ S)
{
  __shared__ float wks[256][32];
  __shared__ float tqs[256][32];
  const int t  = threadIdx.x;
  const int bh = blockIdx.x;
  const int b = bh >> 3, h = bh & 7;
  const float* wkrow = wk + (size_t)t * 256 + h * 32;
  const float* tqrow = TQ + (size_t)b * 65536 + (size_t)t * 256 + h * 32;
  #pragma unroll
  for (int e = 0; e < 32; ++e) {
    wks[t][(e + t) & 31] = wkrow[e];
    tqs[t][(e + t) & 31] = tqrow[e];
  }
  __syncthreads();
  const int d  = t >> 3;
  const int e0 = (t & 7) * 4;
  float acc[4] = {0.f, 0.f, 0.f, 0.f};
  for (int c1 = 0; c1 < 256; ++c1) {
    float kv = wks[c1][(d + c1) & 31];
    #pragma unroll
    for (int j = 0; j < 4; ++j)
      acc[j] += kv * tqs[c1][(e0 + j + c1) & 31];
  }
  #pragma unroll
  for (int j = 0; j < 4; ++j)
    S[bh * 1024 + d * 32 + e0 + j] = acc[j];
}

__global__ __launch_bounds__(256) void norms_part(
    const float* __restrict__ wq, const float* __restrict__ wk,
    const float* __restrict__ TQ, const float* __restrict__ TK,
    float* __restrict__ nqp, float* __restrict__ nkp)
{
  const int o = threadIdx.x;
  const int ch = blockIdx.x & 7;
  const int b  = blockIdx.x >> 3;
  float sq = 0.f, sk = 0.f;
  for (int c1 = ch * 32; c1 < ch * 32 + 32; ++c1) {
    sq += wq[c1 * 256 + o] * TQ[(size_t)b * 65536 + c1 * 256 + o];
    sk += wk[c1 * 256 + o] * TK[(size_t)b * 65536 + c1 * 256 + o];
  }
  nqp[(b * 8 + ch) * 256 + o] = sq;
  nkp[(b * 8 + ch) * 256 + o] = sk;
}

__global__ __launch_bounds__(256) void norms_comb(
    const float* __restrict__ nqp, const float* __restrict__ nkp,
    float* __restrict__ nq, float* __restrict__ nk)
{
  int flat = blockIdx.x * 256 + threadIdx.x;
  int b = flat >> 8, o = flat & 255;
  float sq = 0.f, sk = 0.f;
  #pragma unroll
  for (int ch = 0; ch < 8; ++ch) {
    sq += nqp[(b * 8 + ch) * 256 + o];
    sk += nkp[(b * 8 + ch) * 256 + o];
  }
  nq[flat] = sq;
  nk[flat] = sk;
}

__global__ __launch_bounds__(64) void attn_final(
    const float* __restrict__ S, const float* __restrict__ nq,
    const float* __restrict__ nk, const float* __restrict__ rescale,
    float* __restrict__ attn)
{
  const int bh = blockIdx.x;
  const int b = bh >> 3, h = bh & 7;
  const int d = threadIdx.x;
  if (d >= 32) return;
  const float r = rescale[h];
  const float nkd = fmaxf(sqrtf(nk[b * 256 + h * 32 + d]), 1e-12f);
  float vals[32];
  float mx = -1e30f;
  #pragma unroll
  for (int e = 0; e < 32; ++e) {
    float nqe = fmaxf(sqrtf(nq[b * 256 + h * 32 + e]), 1e-12f);
    float x = S[bh * 1024 + d * 32 + e] / (nkd * nqe) * r;
    vals[e] = x;
    mx = fmaxf(mx, x);
  }
  float sum = 0.f;
  #pragma unroll
  for (int e = 0; e < 32; ++e) { vals[e] = expf(vals[e] - mx); sum += vals[e]; }
  float inv = 1.f / sum;
  #pragma unroll
  for (int e = 0; e < 32; ++e) attn[bh * 1024 + d * 32 + e] = vals[e] * inv;
}

// WbT[b][o][h*32+e] = sum_d attn[b,h,d,e] * projw[h*32+d][o] ; write bf16 H/L
__global__ __launch_bounds__(256) void fold_proj(
    const float* __restrict__ attn, const float* __restrict__ projw,
    u16* __restrict__ WbH, u16* __restrict__ WbL)
{
  const int o  = threadIdx.x;
  const int he = blockIdx.x & 255;
  const int b  = blockIdx.x >> 8;
  const int h = he >> 5, e = he & 31;
  float acc = 0.f;
  #pragma unroll
  for (int d = 0; d < 32; ++d)
    acc += attn[((b * 8 + h) * 32 + d) * 32 + e] * projw[(h * 32 + d) * 256 + o];
  size_t idx = (size_t)b * 65536 + (size_t)o * 256 + he;
  WbH[idx] = (u16)(__builtin_bit_cast(unsigned, acc) >> 16);
  float r = acc - trunc_bf(acc);
  WbL[idx] = (u16)(__builtin_bit_cast(unsigned, r) >> 16);
}

// ---------------------------------------------------------------------------
// m <- m * (1 + sigmoid(dwconv5x5(t) + dwb))  — sliding-window
// ---------------------------------------------------------------------------
__global__ __launch_bounds__(256) void mgm_kernel(
    const float* __restrict__ tin, float* __restrict__ m,
    const float* __restrict__ dww, const float* __restrict__ dwb)
{
  const int c  = threadIdx.x;
  const int blk = blockIdx.x;
  const int xc = (blk & 7) * 32;
  const int y  = (blk >> 3) & 255;
  const int b  = blk >> 11;
  float w[25];
  #pragma unroll
  for (int i = 0; i < 25; ++i) w[i] = dww[c * 25 + i];
  const float bias = dwb[c];
  const float* base = tin + (size_t)b * NPIX * CCH + c;
  int yo[5];
  #pragma unroll
  for (int dy = 0; dy < 5; ++dy) {
    int yy = y + dy - 2;
    yo[dy] = (yy >= 0 && yy <= 255) ? yy * 65536 : -1;
  }
  float col[5][5];
  #pragma unroll
  for (int j = 0; j < 4; ++j) {
    int xx = xc - 2 + j;
    bool xv = (xx >= 0 && xx <= 255);
    #pragma unroll
    for (int dy = 0; dy < 5; ++dy)
      col[j][dy] = (xv && yo[dy] >= 0) ? base[yo[dy] + xx * 256] : 0.f;
  }
  size_t mi = (size_t)b * NPIX * CCH + ((size_t)y * 256 + xc) * 256 + c;
  #pragma unroll 4
  for (int xi = 0; xi < 32; ++xi) {
    int xx = xc + xi + 2;
    bool xv = (xx <= 255);
    #pragma unroll
    for (int dy = 0; dy < 5; ++dy)
      col[4][dy] = (xv && yo[dy] >= 0) ? base[yo[dy] + xx * 256] : 0.f;
    float conv = 0.f;
    #pragma unroll
    for (int dy = 0; dy < 5; ++dy)
      #pragma unroll
      for (int j = 0; j < 5; ++j)
        conv += col[j][dy] * w[dy * 5 + j];
    float sig = 1.f / (1.f + expf(-(conv + bias)));
    m[mi] = m[mi] * (1.f + sig);
    mi += 256;
    #pragma unroll
    for (int j = 0; j < 4; ++j)
      #pragma unroll
      for (int dy = 0; dy < 5; ++dy)
        col[j][dy] = col[j + 1][dy];
  }
}

__global__ __launch_bounds__(256) void pos1_kernel(
    const float* __restrict__ xin, const float* __restrict__ w1,
    float* __restrict__ p1)
{
  const int c  = threadIdx.x;
  const int blk = blockIdx.x;
  const int xc = (blk & 7) * 32;
  const int y  = (blk >> 3) & 255;
  const int b  = blk >> 11;
  float w[9];
  #pragma unroll
  for (int i = 0; i < 9; ++i) w[i] = w1[c * 9 + i];
  const float* base = xin + (size_t)b * NPIX * CCH + c;
  int yo[3];
  #pragma unroll
  for (int dy = 0; dy < 3; ++dy) {
    int yy = y + dy - 1;
    yo[dy] = (yy >= 0 && yy <= 255) ? yy * 65536 : -1;
  }
  float col[3][3];
  #pragma unroll
  for (int j = 0; j < 2; ++j) {
    int xx = xc - 1 + j;
    bool xv = (xx >= 0 && xx <= 255);
    #pragma unroll
    for (int dy = 0; dy < 3; ++dy)
      col[j][dy] = (xv && yo[dy] >= 0) ? base[yo[dy] + xx * 256] : 0.f;
  }
  size_t pi = (size_t)b * NPIX * CCH + ((size_t)y * 256 + xc) * 256 + c;
  #pragma unroll 4
  for (int xi = 0; xi < 32; ++xi) {
    int xx = xc + xi + 1;
    bool xv = (xx <= 255);
    #pragma unroll
    for (int dy = 0; dy < 3; ++dy)
      col[2][dy] = (xv && yo[dy] >= 0) ? base[yo[dy] + xx * 256] : 0.f;
    float conv = 0.f;
    #pragma unroll
    for (int dy = 0; dy < 3; ++dy)
      #pragma unroll
      for (int j = 0; j < 3; ++j)
        conv += col[j][dy] * w[dy * 3 + j];
    float g = 0.5f * conv * (1.f + erff(conv * 0.70710678118654752f));
    p1[pi] = g;
    pi += 256;
    #pragma unroll
    for (int j = 0; j < 2; ++j)
      #pragma unroll
      for (int dy = 0; dy < 3; ++dy)
        col[j][dy] = col[j + 1][dy];
  }
}

__global__ __launch_bounds__(256) void pos2_kernel(
    const float* __restrict__ p1, const float* __restrict__ w2,
    float* __restrict__ out)
{
  const int c  = threadIdx.x;
  const int blk = blockIdx.x;
  const int xc = (blk & 7) * 32;
  const int y  = (blk >> 3) & 255;
  const int b  = blk >> 11;
  float w[9];
  #pragma unroll
  for (int i = 0; i < 9; ++i) w[i] = w2[c * 9 + i];
  const float* base = p1 + (size_t)b * NPIX * CCH + c;
  int yo[3];
  #pragma unroll
  for (int dy = 0; dy < 3; ++dy) {
    int yy = y + dy - 1;
    yo[dy] = (yy >= 0 && yy <= 255) ? yy * 65536 : -1;
  }
  float col[3][3];
  #pragma unroll
  for (int j = 0; j < 2; ++j) {
    int xx = xc - 1 + j;
    bool xv = (xx >= 0 && xx <= 255);
    #pragma unroll
    for (int dy = 0; dy < 3; ++dy)
      col[j][dy] = (xv && yo[dy] >= 0) ? base[yo[dy] + xx * 256] : 0.f;
  }
  size_t pi = (size_t)b * NPIX * CCH + ((size_t)y * 256 + xc) * 256 + c;
  #pragma unroll 4
  for (int xi = 0; xi < 32; ++xi) {
    int xx = xc + xi + 1;
    bool xv = (xx <= 255);
    #pragma unroll
    for (int dy = 0; dy < 3; ++dy)
      col[2][dy] = (xv && yo[dy] >= 0) ? base[yo[dy] + xx * 256] : 0.f;
    float conv = 0.f;
    #pragma unroll
    for (int dy = 0; dy < 3; ++dy)
      #pragma unroll
      for (int j = 0; j < 3; ++j)
        conv += col[j][dy] * w[dy * 3 + j];
    out[pi] = out[pi] + conv;
    pi += 256;
    #pragma unroll
    for (int j = 0; j < 2; ++j)
      #pragma unroll
      for (int dy = 0; dy < 3; ++dy)
        col[j][dy] = col[j + 1][dy];
  }
}

// ---------------------------------------------------------------------------
extern "C" void kernel_launch(void* const* d_in, const int* in_sizes, int n_in,
                              void* d_out, int out_size, void* d_ws, size_t ws_size,
                              hipStream_t stream)
{
  const float* x_in   = (const float*)d_in[0];
  const float* mask   = (const float*)d_in[1];
  const float* wq     = (const float*)d_in[2];
  const float* wk     = (const float*)d_in[3];
  const float* wv     = (const float*)d_in[4];
  const float* rescal = (const float*)d_in[5];
  const float* proj_w = (const float*)d_in[6];
  const float* proj_b = (const float*)d_in[7];
  const float* pos_w1 = (const float*)d_in[8];
  const float* pos_w2 = (const float*)d_in[9];
  const float* c1w    = (const float*)d_in[10];
  const float* c1b    = (const float*)d_in[11];
  const float* c2w    = (const float*)d_in[12];
  const float* c2b    = (const float*)d_in[13];
  const float* dww    = (const float*)d_in[14];
  const float* dwb    = (const float*)d_in[15];
  float* OUT = (float*)d_out;

  // d_ws: A (134.2 MB) + Wb H/L + c1/c2 H/L  (~135.3 MB)
  float* A   = (float*)d_ws;
  u16* WbH = (u16*)(A + (size_t)PTOT * CCH);
  u16* WbL = WbH + 2 * 65536;
  u16* c1H = WbL + 2 * 65536;
  u16* c1L = c1H + 65536;
  u16* c2H = c1L + 65536;
  u16* c2L = c2H + 65536;

  // d_out doubles as scratch; everything dead before the proj GEMMs overwrite it
  float* Gp  = OUT;                              // 2*NCH*65536 fl = 67.1 MB
  float* G   = OUT + (size_t)2 * NCH * 65536;    // 131072
  float* TQ  = G   + 131072;
  float* TK  = TQ  + 131072;
  float* S   = TK  + 131072;                     // 16384
  float* nqp = S   + 16384;                      // 4096
  float* nkp = nqp + 4096;                       // 4096
  float* nq  = nkp + 4096;                       // 512
  float* nk  = nq  + 512;                        // 512
  float* at  = nk  + 512;                        // 16384
  u16* wqH = (u16*)(at + 16384);
  u16* wqL = wqH + 65536;
  u16* wkH = wqL + 65536;
  u16* wkL = wkH + 65536;
  u16* wvH = wkL + 65536;
  u16* wvL = wvH + 65536;

  dim3 gg(PTOT / 128, 2);

  // 0) split conv1x1 weights (needed before OUT is free)
  prep_direct<<<256, 256, 0, stream>>>(c1w, c1H, c1L);
  prep_direct<<<256, 256, 0, stream>>>(c2w, c2H, c2L);
  // 1) mask path: A = mask @ c1w^T + c1b ; OUT(t) = A @ c2w^T + c2b
  gemm_mfma<<<gg, 256, 0, stream>>>(mask, c1H, c1L, c1b, nullptr, A);
  gemm_mfma<<<gg, 256, 0, stream>>>(A,    c2H, c2L, c2b, nullptr, OUT);
  // 2) A <- A * (1 + sigmoid(dwconv5x5(t) + dwb))  == mask_attn
  mgm_kernel<<<4096, 256, 0, stream>>>(OUT, A, dww, dwb);
  // 3) transpose+split remaining weights into OUT scratch (t dead now)
  prep_trans<<<64, 256, 0, stream>>>(wq, wqH, wqL);
  prep_trans<<<64, 256, 0, stream>>>(wk, wkH, wkL);
  prep_trans<<<64, 256, 0, stream>>>(wv, wvH, wvL);
  // 4) Gram via MFMA (deterministic split-K) + reduce
  syrk_mfma<<<2 * NCH, 512, 0, stream>>>(x_in, Gp);
  syrk_reduce<<<128, 256, 0, stream>>>(Gp, G);
  // 5) TQ = G @ wq, TK = G @ wk  (per batch)
  for (int b = 0; b < 2; ++b) {
    gemm_mfma<<<dim3(2, 2), 256, 0, stream>>>(G + (size_t)b * 65536, wqH, wqL,
                                              nullptr, nullptr, TQ + (size_t)b * 65536);
    gemm_mfma<<<dim3(2, 2), 256, 0, stream>>>(G + (size_t)b * 65536, wkH, wkL,
                                              nullptr, nullptr, TK + (size_t)b * 65536);
  }
  // 6) S, norms, softmax, folded projection (bf16 H/L)
  headS_kernel<<<16, 256, 0, stream>>>(wk, TQ, S);
  norms_part<<<16, 256, 0, stream>>>(wq, wk, TQ, TK, nqp, nkp);
  norms_comb<<<2, 256, 0, stream>>>(nqp, nkp, nq, nk);
  attn_final<<<16, 64, 0, stream>>>(S, nq, nk, rescal, at);
  fold_proj<<<512, 256, 0, stream>>>(at, proj_w, WbH, WbL);
  // 7) v' = (x @ wv) * mask_attn  — in place into A
  gemm_mfma<<<gg, 256, 0, stream>>>(x_in, wvH, wvL, nullptr, A, A);
  // 8) OUT = v' @ Wb[b] + proj_b  (fully overwrites d_out incl. scratch)
  {
    dim3 gp(NPIX / 128, 2);
    for (int b = 0; b < 2; ++b)
      gemm_mfma<<<gp, 256, 0, stream>>>(A + (size_t)b * NPIX * CCH,
                                        WbH + (size_t)b * 65536,
                                        WbL + (size_t)b * 65536,
                                        proj_b, nullptr,
                                        OUT + (size_t)b * NPIX * CCH);
  }
  // 9) positional path: A = gelu(conv3(x_in)) ; OUT += conv3(A)
  pos1_kernel<<<4096, 256, 0, stream>>>(x_in, pos_w1, A);
  pos2_kernel<<<4096, 256, 0, stream>>>(A, pos_w2, OUT);
}

// Round 6
// 1419.650 us; speedup vs baseline: 1.7927x; 1.0109x over previous
//
#include <hip/hip_runtime.h>
#include <math.h>

#define CCH 256
#define HEADS 8
#define BATCH 2
#define NPIX 65536
#define PTOT 131072
#define NCH 128                 // syrk K-chunks per batch (512 pixels each)

typedef __attribute__((ext_vector_type(8))) short bfrag;
typedef __attribute__((ext_vector_type(4))) float ffrag;
typedef unsigned short u16;

// k-group swizzle for syrk LDS (unchanged from R5)
#define KSW(row, g) ((((g) ^ (((row) >> 3) & 3)) << 3))

__device__ __forceinline__ float trunc_bf(float f) {
  unsigned u = __builtin_bit_cast(unsigned, f) & 0xffff0000u;
  return __builtin_bit_cast(float, u);
}
// pack hi16 of two floats: low short <- f0, high short <- f1 (bf16 truncation)
__device__ __forceinline__ unsigned pack_hi(float f0, float f1) {
  return __builtin_amdgcn_perm(__builtin_bit_cast(unsigned, f1),
                               __builtin_bit_cast(unsigned, f0), 0x07060302u);
}
__device__ __forceinline__ void split2(float f0, float f1, unsigned& h, unsigned& l) {
  h = pack_hi(f0, f1);
  l = pack_hi(f0 - trunc_bf(f0), f1 - trunc_bf(f1));
}

// ---------------------------------------------------------------------------
// LDS-FREE bf16x3 MFMA GEMM: C[M,256] = A[M,256] @ W^T (+bias) (opt * emul)
// W pre-split bf16 H/L, [n][k] row-major (L2-resident, loaded as fragments).
// A fp32 loaded as fragments straight from global (full-line coalesced across
// the 4 kcg lanes of each row), split to bf16 H/L in registers.
// BM=64, BN=256: block = 4 waves, wave w -> cols w*64..+64, rows m0..m0+64.
// No LDS, no barriers, no bank conflicts. ~150 VGPR -> 3 waves/SIMD.
// In-place safe when emul==C (same thread reads emul[idx] then writes idx).
// ---------------------------------------------------------------------------
__global__ __launch_bounds__(256, 3) void gemm_big(
    const float* __restrict__ A, const u16* __restrict__ WH,
    const u16* __restrict__ WL, const float* __restrict__ bias,
    const float* __restrict__ emul, float* __restrict__ C)
{
  const int t = threadIdx.x;
  const int lane = t & 63, wave = t >> 6;
  const int m0 = blockIdx.x * 64;
  const int wc = wave * 64;
  const int fr = lane & 15, kcg = lane >> 4;

  ffrag acc[4][4];
  #pragma unroll
  for (int i = 0; i < 4; ++i)
    #pragma unroll
    for (int j = 0; j < 4; ++j) acc[i][j] = (ffrag)0.f;

  const float* ap = A + (size_t)(m0 + fr) * 256 + kcg * 8;
  const u16* whp = WH + (size_t)(wc + fr) * 256 + kcg * 8;
  const u16* wlp = WL + (size_t)(wc + fr) * 256 + kcg * 8;

  #pragma unroll 1
  for (int k0 = 0; k0 < 256; k0 += 32) {
    float4 av[8];
    #pragma unroll
    for (int i = 0; i < 4; ++i) {
      av[2*i]   = *(const float4*)(ap + i * 4096 + k0);
      av[2*i+1] = *(const float4*)(ap + i * 4096 + k0 + 4);
    }
    bfrag bh[4], bl[4];
    #pragma unroll
    for (int j = 0; j < 4; ++j) {
      bh[j] = *(const bfrag*)(whp + j * 4096 + k0);
      bl[j] = *(const bfrag*)(wlp + j * 4096 + k0);
    }
    #pragma unroll
    for (int i = 0; i < 4; ++i) {
      unsigned h[4], l[4];
      split2(av[2*i].x,   av[2*i].y,   h[0], l[0]);
      split2(av[2*i].z,   av[2*i].w,   h[1], l[1]);
      split2(av[2*i+1].x, av[2*i+1].y, h[2], l[2]);
      split2(av[2*i+1].z, av[2*i+1].w, h[3], l[3]);
      bfrag ah = __builtin_bit_cast(bfrag, make_uint4(h[0], h[1], h[2], h[3]));
      bfrag al = __builtin_bit_cast(bfrag, make_uint4(l[0], l[1], l[2], l[3]));
      #pragma unroll
      for (int j = 0; j < 4; ++j) {
        acc[i][j] = __builtin_amdgcn_mfma_f32_16x16x32_bf16(ah, bh[j], acc[i][j], 0, 0, 0);
        acc[i][j] = __builtin_amdgcn_mfma_f32_16x16x32_bf16(ah, bl[j], acc[i][j], 0, 0, 0);
        acc[i][j] = __builtin_amdgcn_mfma_f32_16x16x32_bf16(al, bh[j], acc[i][j], 0, 0, 0);
      }
    }
  }

  // C/D layout (HW-verified): col = lane&15, row = (lane>>4)*4 + reg
  const int er = (lane >> 4) * 4, ec = lane & 15;
  #pragma unroll
  for (int i = 0; i < 4; ++i)
    #pragma unroll
    for (int j = 0; j < 4; ++j)
      #pragma unroll
      for (int q = 0; q < 4; ++q) {
        int grow = m0 + i * 16 + er + q;
        int gcol = wc + j * 16 + ec;
        size_t idx = (size_t)grow * 256 + gcol;
        float o = acc[i][j][q];
        if (emul) o *= emul[idx];
        if (bias) o += bias[gcol];
        C[idx] = o;
      }
}

// ---------------------------------------------------------------------------
// SYRK via MFMA: Gp[blk][256][256] = X_chunk^T X_chunk  (unchanged from R5)
// ---------------------------------------------------------------------------
__global__ __launch_bounds__(512, 2) void syrk_mfma(
    const float* __restrict__ X, float* __restrict__ Gp)
{
  __shared__ u16 XsH[256][40], XsL[256][40];
  const int t = threadIdx.x;
  const int blk = blockIdx.x;            // b*NCH + chunk
  const int chunk = blk & (NCH - 1);
  const int b = blk >> 7;                // NCH == 128
  const size_t xb = (size_t)b * NPIX * CCH;
  const int nbase = chunk * (NPIX / NCH);      // 512 pixels per chunk
  const int lane = t & 63, wave = t >> 6;
  const int r0 = wave * 32;
  const int fr = lane & 15, kcg = lane >> 4;
  const int cw = t & 31;                 // staging: c = cw + 32*j  (spacing 1!)
  const int n2 = (t >> 5) * 2;           // staging n-pair 0,2,..,30
  const int gst = n2 >> 3, nin = n2 & 7;

  ffrag acc[2][16];
  #pragma unroll
  for (int i = 0; i < 2; ++i)
    #pragma unroll
    for (int j = 0; j < 16; ++j) acc[i][j] = (ffrag)0.f;

  float fa[8], fb[8];
  auto LOADT = [&](int it) {
    const float* xr = X + xb + (size_t)(nbase + it * 32 + n2) * 256 + cw;
    #pragma unroll
    for (int j = 0; j < 8; ++j) { fa[j] = xr[32 * j]; fb[j] = xr[256 + 32 * j]; }
  };
  LOADT(0);

  const int NIT = (NPIX / NCH) / 32;     // 16
  for (int it = 0; it < NIT; ++it) {
    __syncthreads();
    #pragma unroll
    for (int j = 0; j < 8; ++j) {
      unsigned h, l;
      split2(fa[j], fb[j], h, l);        // low short <- row n2, high <- n2+1
      int c = cw + 32 * j;
      *(unsigned*)&XsH[c][KSW(c, gst) + nin] = h;
      *(unsigned*)&XsL[c][KSW(c, gst) + nin] = l;
    }
    __syncthreads();
    if (it + 1 < NIT) LOADT(it + 1);

    bfrag aH[2], aL[2];
    #pragma unroll
    for (int i = 0; i < 2; ++i) {
      int row = r0 + i * 16 + fr;
      aH[i] = *(const bfrag*)&XsH[row][KSW(row, kcg)];
      aL[i] = *(const bfrag*)&XsL[row][KSW(row, kcg)];
    }
    #pragma unroll
    for (int j = 0; j < 16; ++j) {
      int row = j * 16 + fr;
      bfrag bH = *(const bfrag*)&XsH[row][KSW(row, kcg)];
      bfrag bL = *(const bfrag*)&XsL[row][KSW(row, kcg)];
      #pragma unroll
      for (int i = 0; i < 2; ++i) {
        acc[i][j] = __builtin_amdgcn_mfma_f32_16x16x32_bf16(aH[i], bH, acc[i][j], 0, 0, 0);
        acc[i][j] = __builtin_amdgcn_mfma_f32_16x16x32_bf16(aH[i], bL, acc[i][j], 0, 0, 0);
        acc[i][j] = __builtin_amdgcn_mfma_f32_16x16x32_bf16(aL[i], bH, acc[i][j], 0, 0, 0);
      }
    }
  }
  float* g = Gp + (size_t)blk * 65536;
  const int er = (lane >> 4) * 4, ec = lane & 15;
  #pragma unroll
  for (int i = 0; i < 2; ++i)
    #pragma unroll
    for (int j = 0; j < 16; ++j)
      #pragma unroll
      for (int q = 0; q < 4; ++q)
        g[(r0 + i * 16 + er + q) * 256 + j * 16 + ec] = acc[i][j][q];
}

// G[b] = sum_ch Gp[b][ch]
__global__ __launch_bounds__(256) void syrk_reduce(
    const float* __restrict__ Gp, float* __restrict__ G)
{
  int id = blockIdx.x * 256 + threadIdx.x;   // 0..32767 (float4 units)
  int b = id >> 14;
  int i4 = id & 16383;
  const float4* src = (const float4*)(Gp + (size_t)b * NCH * 65536) + i4;
  float4 s = make_float4(0.f, 0.f, 0.f, 0.f);
  for (int ch = 0; ch < NCH; ++ch) {
    float4 v = src[(size_t)ch * 16384];
    s.x += v.x; s.y += v.y; s.z += v.z; s.w += v.w;
  }
  ((float4*)(G + (size_t)b * 65536))[i4] = s;
}

// ---------------------------------------------------------------------------
// weight preps: split fp32 -> bf16 H/L (direct: [o][c] kept; trans: [c][o]->[o][c])
// ---------------------------------------------------------------------------
__global__ __launch_bounds__(256) void prep_direct(
    const float* __restrict__ src, u16* __restrict__ H, u16* __restrict__ L)
{
  int id = blockIdx.x * 256 + threadIdx.x;
  float f = src[id];
  H[id] = (u16)(__builtin_bit_cast(unsigned, f) >> 16);
  float r = f - trunc_bf(f);
  L[id] = (u16)(__builtin_bit_cast(unsigned, r) >> 16);
}

__global__ __launch_bounds__(256) void prep_trans(
    const float* __restrict__ src, u16* __restrict__ H, u16* __restrict__ L)
{
  __shared__ float tile[32][33];
  const int bx = blockIdx.x & 7, by = blockIdx.x >> 3;
  const int tx = threadIdx.x & 31, ty = threadIdx.x >> 5;
  #pragma unroll
  for (int s = 0; s < 32; s += 8)
    tile[ty + s][tx] = src[(by * 32 + ty + s) * 256 + bx * 32 + tx];
  __syncthreads();
  #pragma unroll
  for (int s = 0; s < 32; s += 8) {
    float f = tile[tx][ty + s];
    int o = bx * 32 + ty + s, c = by * 32 + tx;
    H[o * 256 + c] = (u16)(__builtin_bit_cast(unsigned, f) >> 16);
    float r = f - trunc_bf(f);
    L[o * 256 + c] = (u16)(__builtin_bit_cast(unsigned, r) >> 16);
  }
}

// ---------------------------------------------------------------------------
// S[bh][d][e] = sum_c1 wk[c1][h*32+d] * TQ[b][c1][h*32+e]
// ---------------------------------------------------------------------------
__global__ __launch_bounds__(256) void headS_kernel(
    const float* __restrict__ wk, const float* __restrict__ TQ,
    float* __restrict__ S)
{
  __shared__ float wks[256][32];
  __shared__ float tqs[256][32];
  const int t  = threadIdx.x;
  const int bh = blockIdx.x;
  const int b = bh >> 3, h = bh & 7;
  const float* wkrow = wk + (size_t)t * 256 + h * 32;
  const float* tqrow = TQ + (size_t)b * 65536 + (size_t)t * 256 + h * 32;
  #pragma unroll
  for (int e = 0; e < 32; ++e) {
    wks[t][(e + t) & 31] = wkrow[e];
    tqs[t][(e + t) & 31] = tqrow[e];
  }
  __syncthreads();
  const int d  = t >> 3;
  const int e0 = (t & 7) * 4;
  float acc[4] = {0.f, 0.f, 0.f, 0.f};
  for (int c1 = 0; c1 < 256; ++c1) {
    float kv = wks[c1][(d + c1) & 31];
    #pragma unroll
    for (int j = 0; j < 4; ++j)
      acc[j] += kv * tqs[c1][(e0 + j + c1) & 31];
  }
  #pragma unroll
  for (int j = 0; j < 4; ++j)
    S[bh * 1024 + d * 32 + e0 + j] = acc[j];
}

__global__ __launch_bounds__(256) void norms_part(
    const float* __restrict__ wq, const float* __restrict__ wk,
    const float* __restrict__ TQ, const float* __restrict__ TK,
    float* __restrict__ nqp, float* __restrict__ nkp)
{
  const int o = threadIdx.x;
  const int ch = blockIdx.x & 7;
  const int b  = blockIdx.x >> 3;
  float sq = 0.f, sk = 0.f;
  for (int c1 = ch * 32; c1 < ch * 32 + 32; ++c1) {
    sq += wq[c1 * 256 + o] * TQ[(size_t)b * 65536 + c1 * 256 + o];
    sk += wk[c1 * 256 + o] * TK[(size_t)b * 65536 + c1 * 256 + o];
  }
  nqp[(b * 8 + ch) * 256 + o] = sq;
  nkp[(b * 8 + ch) * 256 + o] = sk;
}

__global__ __launch_bounds__(256) void norms_comb(
    const float* __restrict__ nqp, const float* __restrict__ nkp,
    float* __restrict__ nq, float* __restrict__ nk)
{
  int flat = blockIdx.x * 256 + threadIdx.x;
  int b = flat >> 8, o = flat & 255;
  float sq = 0.f, sk = 0.f;
  #pragma unroll
  for (int ch = 0; ch < 8; ++ch) {
    sq += nqp[(b * 8 + ch) * 256 + o];
    sk += nkp[(b * 8 + ch) * 256 + o];
  }
  nq[flat] = sq;
  nk[flat] = sk;
}

__global__ __launch_bounds__(64) void attn_final(
    const float* __restrict__ S, const float* __restrict__ nq,
    const float* __restrict__ nk, const float* __restrict__ rescale,
    float* __restrict__ attn)
{
  const int bh = blockIdx.x;
  const int b = bh >> 3, h = bh & 7;
  const int d = threadIdx.x;
  if (d >= 32) return;
  const float r = rescale[h];
  const float nkd = fmaxf(sqrtf(nk[b * 256 + h * 32 + d]), 1e-12f);
  float vals[32];
  float mx = -1e30f;
  #pragma unroll
  for (int e = 0; e < 32; ++e) {
    float nqe = fmaxf(sqrtf(nq[b * 256 + h * 32 + e]), 1e-12f);
    float x = S[bh * 1024 + d * 32 + e] / (nkd * nqe) * r;
    vals[e] = x;
    mx = fmaxf(mx, x);
  }
  float sum = 0.f;
  #pragma unroll
  for (int e = 0; e < 32; ++e) { vals[e] = expf(vals[e] - mx); sum += vals[e]; }
  float inv = 1.f / sum;
  #pragma unroll
  for (int e = 0; e < 32; ++e) attn[bh * 1024 + d * 32 + e] = vals[e] * inv;
}

// WbT[b][o][h*32+e] = sum_d attn[b,h,d,e] * projw[h*32+d][o] ; write bf16 H/L
__global__ __launch_bounds__(256) void fold_proj(
    const float* __restrict__ attn, const float* __restrict__ projw,
    u16* __restrict__ WbH, u16* __restrict__ WbL)
{
  const int o  = threadIdx.x;
  const int he = blockIdx.x & 255;
  const int b  = blockIdx.x >> 8;
  const int h = he >> 5, e = he & 31;
  float acc = 0.f;
  #pragma unroll
  for (int d = 0; d < 32; ++d)
    acc += attn[((b * 8 + h) * 32 + d) * 32 + e] * projw[(h * 32 + d) * 256 + o];
  size_t idx = (size_t)b * 65536 + (size_t)o * 256 + he;
  WbH[idx] = (u16)(__builtin_bit_cast(unsigned, acc) >> 16);
  float r = acc - trunc_bf(acc);
  WbL[idx] = (u16)(__builtin_bit_cast(unsigned, r) >> 16);
}

// ---------------------------------------------------------------------------
// m <- m * (1 + sigmoid(dwconv5x5(t) + dwb))  — sliding-window
// ---------------------------------------------------------------------------
__global__ __launch_bounds__(256) void mgm_kernel(
    const float* __restrict__ tin, float* __restrict__ m,
    const float* __restrict__ dww, const float* __restrict__ dwb)
{
  const int c  = threadIdx.x;
  const int blk = blockIdx.x;
  const int xc = (blk & 7) * 32;
  const int y  = (blk >> 3) & 255;
  const int b  = blk >> 11;
  float w[25];
  #pragma unroll
  for (int i = 0; i < 25; ++i) w[i] = dww[c * 25 + i];
  const float bias = dwb[c];
  const float* base = tin + (size_t)b * NPIX * CCH + c;
  int yo[5];
  #pragma unroll
  for (int dy = 0; dy < 5; ++dy) {
    int yy = y + dy - 2;
    yo[dy] = (yy >= 0 && yy <= 255) ? yy * 65536 : -1;
  }
  float col[5][5];
  #pragma unroll
  for (int j = 0; j < 4; ++j) {
    int xx = xc - 2 + j;
    bool xv = (xx >= 0 && xx <= 255);
    #pragma unroll
    for (int dy = 0; dy < 5; ++dy)
      col[j][dy] = (xv && yo[dy] >= 0) ? base[yo[dy] + xx * 256] : 0.f;
  }
  size_t mi = (size_t)b * NPIX * CCH + ((size_t)y * 256 + xc) * 256 + c;
  #pragma unroll 4
  for (int xi = 0; xi < 32; ++xi) {
    int xx = xc + xi + 2;
    bool xv = (xx <= 255);
    #pragma unroll
    for (int dy = 0; dy < 5; ++dy)
      col[4][dy] = (xv && yo[dy] >= 0) ? base[yo[dy] + xx * 256] : 0.f;
    float conv = 0.f;
    #pragma unroll
    for (int dy = 0; dy < 5; ++dy)
      #pragma unroll
      for (int j = 0; j < 5; ++j)
        conv += col[j][dy] * w[dy * 5 + j];
    float sig = 1.f / (1.f + expf(-(conv + bias)));
    m[mi] = m[mi] * (1.f + sig);
    mi += 256;
    #pragma unroll
    for (int j = 0; j < 4; ++j)
      #pragma unroll
      for (int dy = 0; dy < 5; ++dy)
        col[j][dy] = col[j + 1][dy];
  }
}

__global__ __launch_bounds__(256) void pos1_kernel(
    const float* __restrict__ xin, const float* __restrict__ w1,
    float* __restrict__ p1)
{
  const int c  = threadIdx.x;
  const int blk = blockIdx.x;
  const int xc = (blk & 7) * 32;
  const int y  = (blk >> 3) & 255;
  const int b  = blk >> 11;
  float w[9];
  #pragma unroll
  for (int i = 0; i < 9; ++i) w[i] = w1[c * 9 + i];
  const float* base = xin + (size_t)b * NPIX * CCH + c;
  int yo[3];
  #pragma unroll
  for (int dy = 0; dy < 3; ++dy) {
    int yy = y + dy - 1;
    yo[dy] = (yy >= 0 && yy <= 255) ? yy * 65536 : -1;
  }
  float col[3][3];
  #pragma unroll
  for (int j = 0; j < 2; ++j) {
    int xx = xc - 1 + j;
    bool xv = (xx >= 0 && xx <= 255);
    #pragma unroll
    for (int dy = 0; dy < 3; ++dy)
      col[j][dy] = (xv && yo[dy] >= 0) ? base[yo[dy] + xx * 256] : 0.f;
  }
  size_t pi = (size_t)b * NPIX * CCH + ((size_t)y * 256 + xc) * 256 + c;
  #pragma unroll 4
  for (int xi = 0; xi < 32; ++xi) {
    int xx = xc + xi + 1;
    bool xv = (xx <= 255);
    #pragma unroll
    for (int dy = 0; dy < 3; ++dy)
      col[2][dy] = (xv && yo[dy] >= 0) ? base[yo[dy] + xx * 256] : 0.f;
    float conv = 0.f;
    #pragma unroll
    for (int dy = 0; dy < 3; ++dy)
      #pragma unroll
      for (int j = 0; j < 3; ++j)
        conv += col[j][dy] * w[dy * 3 + j];
    float g = 0.5f * conv * (1.f + erff(conv * 0.70710678118654752f));
    p1[pi] = g;
    pi += 256;
    #pragma unroll
    for (int j = 0; j < 2; ++j)
      #pragma unroll
      for (int dy = 0; dy < 3; ++dy)
        col[j][dy] = col[j + 1][dy];
  }
}

__global__ __launch_bounds__(256) void pos2_kernel(
    const float* __restrict__ p1, const float* __restrict__ w2,
    float* __restrict__ out)
{
  const int c  = threadIdx.x;
  const int blk = blockIdx.x;
  const int xc = (blk & 7) * 32;
  const int y  = (blk >> 3) & 255;
  const int b  = blk >> 11;
  float w[9];
  #pragma unroll
  for (int i = 0; i < 9; ++i) w[i] = w2[c * 9 + i];
  const float* base = p1 + (size_t)b * NPIX * CCH + c;
  int yo[3];
  #pragma unroll
  for (int dy = 0; dy < 3; ++dy) {
    int yy = y + dy - 1;
    yo[dy] = (yy >= 0 && yy <= 255) ? yy * 65536 : -1;
  }
  float col[3][3];
  #pragma unroll
  for (int j = 0; j < 2; ++j) {
    int xx = xc - 1 + j;
    bool xv = (xx >= 0 && xx <= 255);
    #pragma unroll
    for (int dy = 0; dy < 3; ++dy)
      col[j][dy] = (xv && yo[dy] >= 0) ? base[yo[dy] + xx * 256] : 0.f;
  }
  size_t pi = (size_t)b * NPIX * CCH + ((size_t)y * 256 + xc) * 256 + c;
  #pragma unroll 4
  for (int xi = 0; xi < 32; ++xi) {
    int xx = xc + xi + 1;
    bool xv = (xx <= 255);
    #pragma unroll
    for (int dy = 0; dy < 3; ++dy)
      col[2][dy] = (xv && yo[dy] >= 0) ? base[yo[dy] + xx * 256] : 0.f;
    float conv = 0.f;
    #pragma unroll
    for (int dy = 0; dy < 3; ++dy)
      #pragma unroll
      for (int j = 0; j < 3; ++j)
        conv += col[j][dy] * w[dy * 3 + j];
    out[pi] = out[pi] + conv;
    pi += 256;
    #pragma unroll
    for (int j = 0; j < 2; ++j)
      #pragma unroll
      for (int dy = 0; dy < 3; ++dy)
        col[j][dy] = col[j + 1][dy];
  }
}

// ---------------------------------------------------------------------------
extern "C" void kernel_launch(void* const* d_in, const int* in_sizes, int n_in,
                              void* d_out, int out_size, void* d_ws, size_t ws_size,
                              hipStream_t stream)
{
  const float* x_in   = (const float*)d_in[0];
  const float* mask   = (const float*)d_in[1];
  const float* wq     = (const float*)d_in[2];
  const float* wk     = (const float*)d_in[3];
  const float* wv     = (const float*)d_in[4];
  const float* rescal = (const float*)d_in[5];
  const float* proj_w = (const float*)d_in[6];
  const float* proj_b = (const float*)d_in[7];
  const float* pos_w1 = (const float*)d_in[8];
  const float* pos_w2 = (const float*)d_in[9];
  const float* c1w    = (const float*)d_in[10];
  const float* c1b    = (const float*)d_in[11];
  const float* c2w    = (const float*)d_in[12];
  const float* c2b    = (const float*)d_in[13];
  const float* dww    = (const float*)d_in[14];
  const float* dwb    = (const float*)d_in[15];
  float* OUT = (float*)d_out;

  // d_ws: A (134.2 MB) + Wb H/L + c1/c2 H/L  (~135.3 MB)
  float* A   = (float*)d_ws;
  u16* WbH = (u16*)(A + (size_t)PTOT * CCH);
  u16* WbL = WbH + 2 * 65536;
  u16* c1H = WbL + 2 * 65536;
  u16* c1L = c1H + 65536;
  u16* c2H = c1L + 65536;
  u16* c2L = c2H + 65536;

  // d_out doubles as scratch; everything dead before the proj GEMMs overwrite it
  float* Gp  = OUT;                              // 2*NCH*65536 fl = 67.1 MB
  float* G   = OUT + (size_t)2 * NCH * 65536;    // 131072
  float* TQ  = G   + 131072;
  float* TK  = TQ  + 131072;
  float* S   = TK  + 131072;                     // 16384
  float* nqp = S   + 16384;                      // 4096
  float* nkp = nqp + 4096;                       // 4096
  float* nq  = nkp + 4096;                       // 512
  float* nk  = nq  + 512;                        // 512
  float* at  = nk  + 512;                        // 16384
  u16* wqH = (u16*)(at + 16384);
  u16* wqL = wqH + 65536;
  u16* wkH = wqL + 65536;
  u16* wkL = wkH + 65536;
  u16* wvH = wkL + 65536;
  u16* wvL = wvH + 65536;

  // 0) split conv1x1 weights (needed before OUT is free)
  prep_direct<<<256, 256, 0, stream>>>(c1w, c1H, c1L);
  prep_direct<<<256, 256, 0, stream>>>(c2w, c2H, c2L);
  // 1) mask path: A = mask @ c1w^T + c1b ; OUT(t) = A @ c2w^T + c2b
  gemm_big<<<PTOT / 64, 256, 0, stream>>>(mask, c1H, c1L, c1b, nullptr, A);
  gemm_big<<<PTOT / 64, 256, 0, stream>>>(A,    c2H, c2L, c2b, nullptr, OUT);
  // 2) A <- A * (1 + sigmoid(dwconv5x5(t) + dwb))  == mask_attn
  mgm_kernel<<<4096, 256, 0, stream>>>(OUT, A, dww, dwb);
  // 3) transpose+split remaining weights into OUT scratch (t dead now)
  prep_trans<<<64, 256, 0, stream>>>(wq, wqH, wqL);
  prep_trans<<<64, 256, 0, stream>>>(wk, wkH, wkL);
  prep_trans<<<64, 256, 0, stream>>>(wv, wvH, wvL);
  // 4) Gram via MFMA (deterministic split-K) + reduce
  syrk_mfma<<<2 * NCH, 512, 0, stream>>>(x_in, Gp);
  syrk_reduce<<<128, 256, 0, stream>>>(Gp, G);
  // 5) TQ = G @ wq, TK = G @ wk  (per batch)
  for (int b = 0; b < 2; ++b) {
    gemm_big<<<4, 256, 0, stream>>>(G + (size_t)b * 65536, wqH, wqL,
                                    nullptr, nullptr, TQ + (size_t)b * 65536);
    gemm_big<<<4, 256, 0, stream>>>(G + (size_t)b * 65536, wkH, wkL,
                                    nullptr, nullptr, TK + (size_t)b * 65536);
  }
  // 6) S, norms, softmax, folded projection (bf16 H/L)
  headS_kernel<<<16, 256, 0, stream>>>(wk, TQ, S);
  norms_part<<<16, 256, 0, stream>>>(wq, wk, TQ, TK, nqp, nkp);
  norms_comb<<<2, 256, 0, stream>>>(nqp, nkp, nq, nk);
  attn_final<<<16, 64, 0, stream>>>(S, nq, nk, rescal, at);
  fold_proj<<<512, 256, 0, stream>>>(at, proj_w, WbH, WbL);
  // 7) v' = (x @ wv) * mask_attn  — in place into A
  gemm_big<<<PTOT / 64, 256, 0, stream>>>(x_in, wvH, wvL, nullptr, A, A);
  // 8) OUT = v' @ Wb[b] + proj_b  (fully overwrites d_out incl. scratch)
  for (int b = 0; b < 2; ++b)
    gemm_big<<<NPIX / 64, 256, 0, stream>>>(A + (size_t)b * NPIX * CCH,
                                            WbH + (size_t)b * 65536,
                                            WbL + (size_t)b * 65536,
                                            proj_b, nullptr,
                                            OUT + (size_t)b * NPIX * CCH);
  // 9) positional path: A = gelu(conv3(x_in)) ; OUT += conv3(A)
  pos1_kernel<<<4096, 256, 0, stream>>>(x_in, pos_w1, A);
  pos2_kernel<<<4096, 256, 0, stream>>>(A, pos_w2, OUT);
}